// Round 2
// baseline (12965.300 us; speedup 1.0000x reference)
//
#include <hip/hip_runtime.h>

#define BATCH 8
#define SEQ   4096
#define DM    256
#define DI    512
#define DS    16
#define DTR   16
#define NL    6
#define MROWS (BATCH*SEQ)   // 32768

typedef float  f32x4 __attribute__((ext_vector_type(4)));
typedef __bf16 bf16x8 __attribute__((ext_vector_type(8)));

__device__ __forceinline__ float bf2f(unsigned short b){
  unsigned u = ((unsigned)b) << 16;
  return __builtin_bit_cast(float, u);
}
__device__ __forceinline__ unsigned short f2bf(float f){
  unsigned u = __builtin_bit_cast(unsigned, f);
  unsigned r = u + 0x7FFFu + ((u >> 16) & 1u);
  return (unsigned short)(r >> 16);
}

// ---------------- transpose x [B,256,L] f32 -> h [(b*L+l)*256+c] f32 ----------------
__global__ void transpose_in(const float* __restrict__ x, float* __restrict__ h){
  __shared__ float tile[32][33];
  int b = blockIdx.z;
  int l0 = blockIdx.x*32, c0 = blockIdx.y*32;
  int tx = threadIdx.x, ty = threadIdx.y;
  #pragma unroll
  for (int i=0;i<4;i++)
    tile[ty+8*i][tx] = x[((size_t)(b*DM + c0+ty+8*i))*SEQ + l0 + tx];
  __syncthreads();
  #pragma unroll
  for (int i=0;i<4;i++)
    h[((size_t)(b*SEQ + l0+ty+8*i))*DM + c0 + tx] = tile[tx][ty+8*i];
}

// ---------------- transpose h -> out [B,256,L] ----------------
__global__ void transpose_out(const float* __restrict__ h, float* __restrict__ out){
  __shared__ float tile[32][33];
  int b = blockIdx.z;
  int l0 = blockIdx.x*32, c0 = blockIdx.y*32;
  int tx = threadIdx.x, ty = threadIdx.y;
  #pragma unroll
  for (int i=0;i<4;i++)
    tile[ty+8*i][tx] = h[((size_t)(b*SEQ + l0+ty+8*i))*DM + c0 + tx];
  __syncthreads();
  #pragma unroll
  for (int i=0;i<4;i++)
    out[((size_t)(b*DM + c0+ty+8*i))*SEQ + l0 + tx] = tile[tx][ty+8*i];
}

// ---------------- f32 -> bf16 convert ----------------
__global__ void cvt_bf16(const float* __restrict__ in, unsigned short* __restrict__ out, int n){
  int i = blockIdx.x*256 + threadIdx.x;
  if (i < n) out[i] = f2bf(in[i]);
}

// ---------------- LayerNorm over 256 channels, one wave per row, bf16 out ----------------
__global__ void ln_kernel(const float* __restrict__ h, const float* __restrict__ g,
                          const float* __restrict__ bta, unsigned short* __restrict__ out){
  int wave = threadIdx.x >> 6, lane = threadIdx.x & 63;
  size_t row = (size_t)blockIdx.x*4 + wave;
  const float* hr = h + row*DM;
  f32x4 v = *reinterpret_cast<const f32x4*>(hr + lane*4);
  float s  = v.x + v.y + v.z + v.w;
  float sq = v.x*v.x + v.y*v.y + v.z*v.z + v.w*v.w;
  #pragma unroll
  for (int off=32; off; off>>=1){
    s  += __shfl_xor(s,  off, 64);
    sq += __shfl_xor(sq, off, 64);
  }
  float mean = s * (1.f/DM);
  float var  = sq * (1.f/DM) - mean*mean;
  float rstd = rsqrtf(var + 1e-5f);
  f32x4 gg = *reinterpret_cast<const f32x4*>(g   + lane*4);
  f32x4 bb = *reinterpret_cast<const f32x4*>(bta + lane*4);
  unsigned short* o = out + row*DM + lane*4;
  o[0] = f2bf((v.x-mean)*rstd*gg.x + bb.x);
  o[1] = f2bf((v.y-mean)*rstd*gg.y + bb.y);
  o[2] = f2bf((v.z-mean)*rstd*gg.z + bb.z);
  o[3] = f2bf((v.w-mean)*rstd*gg.w + bb.w);
}

// ---------------- bf16 MFMA GEMM: C[M,N] = A[M,K] @ W[N,K]^T ----------------
// OUTMODE 0: f32 store, 1: bf16 store, 2: f32 accumulate (C += )
template<int OUTMODE>
__global__ void gemm_kernel(const unsigned short* __restrict__ A,
                            const unsigned short* __restrict__ W,
                            void* __restrict__ Cout, int N, int K){
  int wave = threadIdx.x >> 6, lane = threadIdx.x & 63;
  int mbase = blockIdx.y*64 + wave*16;
  int nbase = blockIdx.x*64;
  int l15 = lane & 15, kseg = (lane >> 4) * 8;
  const unsigned short* Ap = A + (size_t)(mbase + l15)*K + kseg;
  const unsigned short* Wp0; const unsigned short* Wp1;
  const unsigned short* Wp2; const unsigned short* Wp3;
  {
    int c0 = nbase + 0*16 + l15; if (c0 >= N) c0 = N-1;
    int c1 = nbase + 1*16 + l15; if (c1 >= N) c1 = N-1;
    int c2 = nbase + 2*16 + l15; if (c2 >= N) c2 = N-1;
    int c3 = nbase + 3*16 + l15; if (c3 >= N) c3 = N-1;
    Wp0 = W + (size_t)c0*K + kseg; Wp1 = W + (size_t)c1*K + kseg;
    Wp2 = W + (size_t)c2*K + kseg; Wp3 = W + (size_t)c3*K + kseg;
  }
  f32x4 acc0 = {0.f,0.f,0.f,0.f}, acc1 = {0.f,0.f,0.f,0.f};
  f32x4 acc2 = {0.f,0.f,0.f,0.f}, acc3 = {0.f,0.f,0.f,0.f};
  #pragma unroll 2
  for (int k = 0; k < K; k += 32){
    bf16x8 a  = *reinterpret_cast<const bf16x8*>(Ap  + k);
    bf16x8 b0 = *reinterpret_cast<const bf16x8*>(Wp0 + k);
    bf16x8 b1 = *reinterpret_cast<const bf16x8*>(Wp1 + k);
    bf16x8 b2 = *reinterpret_cast<const bf16x8*>(Wp2 + k);
    bf16x8 b3 = *reinterpret_cast<const bf16x8*>(Wp3 + k);
    acc0 = __builtin_amdgcn_mfma_f32_16x16x32_bf16(a, b0, acc0, 0,0,0);
    acc1 = __builtin_amdgcn_mfma_f32_16x16x32_bf16(a, b1, acc1, 0,0,0);
    acc2 = __builtin_amdgcn_mfma_f32_16x16x32_bf16(a, b2, acc2, 0,0,0);
    acc3 = __builtin_amdgcn_mfma_f32_16x16x32_bf16(a, b3, acc3, 0,0,0);
  }
  int rbase = mbase + (lane >> 4)*4;
  f32x4 accs[4] = {acc0, acc1, acc2, acc3};
  #pragma unroll
  for (int f=0; f<4; f++){
    int col = nbase + f*16 + l15;
    if (col < N){
      #pragma unroll
      for (int j=0; j<4; j++){
        size_t idx = (size_t)(rbase + j)*N + col;
        if (OUTMODE == 0)      ((float*)Cout)[idx] = accs[f][j];
        else if (OUTMODE == 1) ((unsigned short*)Cout)[idx] = f2bf(accs[f][j]);
        else                   ((float*)Cout)[idx] += accs[f][j];
      }
    }
  }
}

// ---------------- depthwise causal conv(4) + bias + SiLU: xz[:, :512] -> u bf16 ----------------
__global__ void conv_kernel(const unsigned short* __restrict__ xz, const float* __restrict__ cw,
                            const float* __restrict__ cb, unsigned short* __restrict__ u){
  size_t idx = (size_t)blockIdx.x*256 + threadIdx.x;  // over MROWS*512
  int d = (int)(idx & 511);
  size_t row = idx >> 9;
  int l = (int)(row & (SEQ-1));
  float w0 = cw[d*4+0], w1 = cw[d*4+1], w2 = cw[d*4+2], w3 = cw[d*4+3];
  float acc = cb[d];
  const unsigned short* base = xz + row*1024 + d;
  acc += bf2f(base[0]) * w3;
  if (l >= 1) acc += bf2f(*(base - 1024)) * w2;
  if (l >= 2) acc += bf2f(*(base - 2048)) * w1;
  if (l >= 3) acc += bf2f(*(base - 3072)) * w0;
  float s = acc / (1.f + expf(-acc));
  u[row*512 + d] = f2bf(s);
}

// ---------------- delta = softplus(dt @ W_dt^T + b_dt), bf16 out ----------------
__global__ void delta_kernel(const float* __restrict__ xdb, const float* __restrict__ Wdt,
                             const float* __restrict__ bdt, unsigned short* __restrict__ delta){
  __shared__ float sdt[16];
  size_t row = blockIdx.x;
  int d = threadIdx.x;  // 512 threads
  if (d < 16) sdt[d] = xdb[row*48 + d];
  __syncthreads();
  f32x4 w0 = *reinterpret_cast<const f32x4*>(Wdt + d*16 + 0);
  f32x4 w1 = *reinterpret_cast<const f32x4*>(Wdt + d*16 + 4);
  f32x4 w2 = *reinterpret_cast<const f32x4*>(Wdt + d*16 + 8);
  f32x4 w3 = *reinterpret_cast<const f32x4*>(Wdt + d*16 + 12);
  float acc = bdt[d];
  acc += sdt[0]*w0.x + sdt[1]*w0.y + sdt[2]*w0.z + sdt[3]*w0.w;
  acc += sdt[4]*w1.x + sdt[5]*w1.y + sdt[6]*w1.z + sdt[7]*w1.w;
  acc += sdt[8]*w2.x + sdt[9]*w2.y + sdt[10]*w2.z + sdt[11]*w2.w;
  acc += sdt[12]*w3.x + sdt[13]*w3.y + sdt[14]*w3.z + sdt[15]*w3.w;
  float sp = (acc > 20.f) ? acc : log1pf(expf(acc));
  delta[row*512 + d] = f2bf(sp);
}

// ---------------- SSM scan: thread per (b,d,n), y = C.h + D*u folded, bf16 y ----------------
__global__ void __launch_bounds__(256) scan_kernel(
    const unsigned short* __restrict__ delta, const unsigned short* __restrict__ u,
    const float* __restrict__ xdb, const float* __restrict__ Alog,
    const float* __restrict__ Dp, unsigned short* __restrict__ y){
  int wave = threadIdx.x >> 6, lane = threadIdx.x & 63;
  int n = lane & 15;
  int cloc = (wave << 2) | (lane >> 4);
  int b  = blockIdx.x >> 5;
  int cg = blockIdx.x & 31;
  int d  = cg*16 + cloc;
  float A  = -expf(Alog[d*16 + n]);
  float Dd = Dp[d];
  float h = 0.f;
  size_t rowbase = (size_t)b * SEQ;
  const unsigned short* dptr = delta + rowbase*512 + d;
  const unsigned short* uptr = u     + rowbase*512 + d;
  const float*          bptr = xdb   + rowbase*48 + 16 + n;
  const float*          cptr = xdb   + rowbase*48 + 32 + n;
  unsigned short*       yptr = y     + rowbase*512 + d;
  #pragma unroll 8
  for (int l=0; l<SEQ; l++){
    float dv = bf2f(dptr[(size_t)l*512]);
    float uv = bf2f(uptr[(size_t)l*512]);
    float bm = bptr[(size_t)l*48];
    float cm = cptr[(size_t)l*48];
    float a = __expf(dv * A);
    h = a*h + (dv*uv)*bm;
    float p = h * cm;
    p += __shfl_xor(p, 1, 64);
    p += __shfl_xor(p, 2, 64);
    p += __shfl_xor(p, 4, 64);
    p += __shfl_xor(p, 8, 64);
    if (n == 0) yptr[(size_t)l*512] = f2bf(p + Dd*uv);
  }
}

// ---------------- gate: g = y * silu(z), write bf16 over u buffer ----------------
__global__ void gate_kernel(const unsigned short* __restrict__ y, const unsigned short* __restrict__ xz,
                            unsigned short* __restrict__ g){
  size_t idx = (size_t)blockIdx.x*256 + threadIdx.x;
  size_t row = idx >> 9; int d = (int)(idx & 511);
  float z = bf2f(xz[row*1024 + 512 + d]);
  float gv = bf2f(y[idx]) * (z / (1.f + expf(-z)));
  g[idx] = f2bf(gv);
}

extern "C" void kernel_launch(void* const* d_in, const int* in_sizes, int n_in,
                              void* d_out, int out_size, void* d_ws, size_t ws_size,
                              hipStream_t stream){
  (void)in_sizes; (void)n_in; (void)out_size; (void)ws_size;
  const float* x      = (const float*)d_in[0];
  const float* W_in   = (const float*)d_in[1];
  const float* conv_w = (const float*)d_in[2];
  const float* conv_b = (const float*)d_in[3];
  const float* W_x    = (const float*)d_in[4];
  const float* W_dt   = (const float*)d_in[5];
  const float* b_dt   = (const float*)d_in[6];
  const float* A_log  = (const float*)d_in[7];
  const float* Dp     = (const float*)d_in[8];
  const float* W_out  = (const float*)d_in[9];
  const float* ln_g   = (const float*)d_in[10];
  const float* ln_b   = (const float*)d_in[11];
  float* out = (float*)d_out;

  // workspace carve-up (~179 MB total; y lives in d_out)
  char* p = (char*)d_ws;
  auto alloc = [&](size_t bytes)->char*{
    char* r = p; p += (bytes + 255) & ~(size_t)255; return r;
  };
  float*          hbuf   = (float*)alloc((size_t)MROWS*DM*4);           // 33.5 MB residual f32
  unsigned short* xzb    = (unsigned short*)alloc((size_t)MROWS*1024*2);// 67 MB
  unsigned short* ubuf   = (unsigned short*)alloc((size_t)MROWS*DI*2);  // 33.5 MB
  unsigned short* lnb    = (unsigned short*)alloc((size_t)MROWS*DI*2);  // 33.5 MB shared: lnb [M,256] / delta [M,512]
  unsigned short* dlt    = lnb;                                         // alias (disjoint live ranges)
  float*          xdb    = (float*)alloc((size_t)MROWS*48*4);           // 6.3 MB
  unsigned short* WinB   = (unsigned short*)alloc((size_t)NL*1024*DM*2);// 3.1 MB
  unsigned short* WxB    = (unsigned short*)alloc((size_t)NL*48*DI*2);  // 0.3 MB
  unsigned short* WoutB  = (unsigned short*)alloc((size_t)NL*DM*DI*2);  // 1.6 MB
  unsigned short* ybuf   = (unsigned short*)d_out;                      // 33.5 MB scratch in d_out

  // weight conversion
  {
    int n1 = NL*1024*DM;  cvt_bf16<<<(n1+255)/256, 256, 0, stream>>>(W_in,  WinB,  n1);
    int n2 = NL*48*DI;    cvt_bf16<<<(n2+255)/256, 256, 0, stream>>>(W_x,   WxB,   n2);
    int n3 = NL*DM*DI;    cvt_bf16<<<(n3+255)/256, 256, 0, stream>>>(W_out, WoutB, n3);
  }

  transpose_in<<<dim3(SEQ/32, DM/32, BATCH), dim3(32,8), 0, stream>>>(x, hbuf);

  for (int i=0; i<NL; i++){
    const unsigned short* Wi = WinB  + (size_t)i*1024*DM;
    const unsigned short* Wx = WxB   + (size_t)i*48*DI;
    const unsigned short* Wo = WoutB + (size_t)i*DM*DI;

    ln_kernel<<<MROWS/4, 256, 0, stream>>>(hbuf, ln_g + i*DM, ln_b + i*DM, lnb);

    // xz = ln @ W_in^T  [M,1024] bf16
    gemm_kernel<1><<<dim3(1024/64, MROWS/64), 256, 0, stream>>>(lnb, Wi, xzb, 1024, DM);

    conv_kernel<<<(size_t)MROWS*DI/256, 256, 0, stream>>>(xzb, conv_w + (size_t)i*DI*4,
                                                          conv_b + i*DI, ubuf);

    // xdb = u @ W_x^T  [M,48] f32
    gemm_kernel<0><<<dim3(1, MROWS/64), 256, 0, stream>>>(ubuf, Wx, xdb, 48, DI);

    delta_kernel<<<MROWS, 512, 0, stream>>>(xdb, W_dt + (size_t)i*DI*DTR, b_dt + i*DI, dlt);

    scan_kernel<<<BATCH*32, 256, 0, stream>>>(dlt, ubuf, xdb,
                                              A_log + (size_t)i*DI*DS, Dp + i*DI, ybuf);

    gate_kernel<<<(size_t)MROWS*DI/256, 256, 0, stream>>>(ybuf, xzb, ubuf);

    // h += g @ W_out^T  [M,256] f32 accumulate
    gemm_kernel<2><<<dim3(DM/64, MROWS/64), 256, 0, stream>>>(ubuf, Wo, hbuf, DM, DI);
  }

  transpose_out<<<dim3(SEQ/32, DM/32, BATCH), dim3(32,8), 0, stream>>>(hbuf, out);
}

// Round 3
// 4558.616 us; speedup vs baseline: 2.8441x; 2.8441x over previous
//
#include <hip/hip_runtime.h>

#define BATCH 8
#define SEQ   4096
#define DM    256
#define DI    512
#define DS    16
#define DTR   16
#define NL    6
#define MROWS (BATCH*SEQ)   // 32768
#define CCH   32            // scan chunks
#define CL    (SEQ/CCH)     // 128 steps per chunk
#define SC    (BATCH*DI*DS) // 65536 per-chunk scan states

typedef float  f32x4 __attribute__((ext_vector_type(4)));
typedef __bf16 bf16x8 __attribute__((ext_vector_type(8)));

__device__ __forceinline__ float bf2f(unsigned short b){
  unsigned u = ((unsigned)b) << 16;
  return __builtin_bit_cast(float, u);
}
__device__ __forceinline__ unsigned short f2bf(float f){
  unsigned u = __builtin_bit_cast(unsigned, f);
  unsigned r = u + 0x7FFFu + ((u >> 16) & 1u);
  return (unsigned short)(r >> 16);
}

// ---------------- transpose x [B,256,L] f32 -> h [(b*L+l)*256+c] f32 ----------------
__global__ void transpose_in(const float* __restrict__ x, float* __restrict__ h){
  __shared__ float tile[32][33];
  int b = blockIdx.z;
  int l0 = blockIdx.x*32, c0 = blockIdx.y*32;
  int tx = threadIdx.x, ty = threadIdx.y;
  #pragma unroll
  for (int i=0;i<4;i++)
    tile[ty+8*i][tx] = x[((size_t)(b*DM + c0+ty+8*i))*SEQ + l0 + tx];
  __syncthreads();
  #pragma unroll
  for (int i=0;i<4;i++)
    h[((size_t)(b*SEQ + l0+ty+8*i))*DM + c0 + tx] = tile[tx][ty+8*i];
}

// ---------------- transpose h -> out [B,256,L] ----------------
__global__ void transpose_out(const float* __restrict__ h, float* __restrict__ out){
  __shared__ float tile[32][33];
  int b = blockIdx.z;
  int l0 = blockIdx.x*32, c0 = blockIdx.y*32;
  int tx = threadIdx.x, ty = threadIdx.y;
  #pragma unroll
  for (int i=0;i<4;i++)
    tile[ty+8*i][tx] = h[((size_t)(b*SEQ + l0+ty+8*i))*DM + c0 + tx];
  __syncthreads();
  #pragma unroll
  for (int i=0;i<4;i++)
    out[((size_t)(b*DM + c0+ty+8*i))*SEQ + l0 + tx] = tile[tx][ty+8*i];
}

// ---------------- f32 -> bf16 convert ----------------
__global__ void cvt_bf16(const float* __restrict__ in, unsigned short* __restrict__ out, int n){
  int i = blockIdx.x*256 + threadIdx.x;
  if (i < n) out[i] = f2bf(in[i]);
}

// ---------------- LayerNorm over 256 channels, one wave per row, bf16 out ----------------
__global__ void ln_kernel(const float* __restrict__ h, const float* __restrict__ g,
                          const float* __restrict__ bta, unsigned short* __restrict__ out){
  int wave = threadIdx.x >> 6, lane = threadIdx.x & 63;
  size_t row = (size_t)blockIdx.x*4 + wave;
  const float* hr = h + row*DM;
  f32x4 v = *reinterpret_cast<const f32x4*>(hr + lane*4);
  float s  = v.x + v.y + v.z + v.w;
  float sq = v.x*v.x + v.y*v.y + v.z*v.z + v.w*v.w;
  #pragma unroll
  for (int off=32; off; off>>=1){
    s  += __shfl_xor(s,  off, 64);
    sq += __shfl_xor(sq, off, 64);
  }
  float mean = s * (1.f/DM);
  float var  = sq * (1.f/DM) - mean*mean;
  float rstd = rsqrtf(var + 1e-5f);
  f32x4 gg = *reinterpret_cast<const f32x4*>(g   + lane*4);
  f32x4 bb = *reinterpret_cast<const f32x4*>(bta + lane*4);
  unsigned short* o = out + row*DM + lane*4;
  o[0] = f2bf((v.x-mean)*rstd*gg.x + bb.x);
  o[1] = f2bf((v.y-mean)*rstd*gg.y + bb.y);
  o[2] = f2bf((v.z-mean)*rstd*gg.z + bb.z);
  o[3] = f2bf((v.w-mean)*rstd*gg.w + bb.w);
}

// ---------------- bf16 MFMA GEMM: C[M,N] = A[M,K] @ W[N,K]^T ----------------
// OUTMODE 0: f32 store, 1: bf16 store, 2: f32 accumulate (C += )
template<int OUTMODE>
__global__ void gemm_kernel(const unsigned short* __restrict__ A,
                            const unsigned short* __restrict__ W,
                            void* __restrict__ Cout, int N, int K){
  int wave = threadIdx.x >> 6, lane = threadIdx.x & 63;
  int mbase = blockIdx.y*64 + wave*16;
  int nbase = blockIdx.x*64;
  int l15 = lane & 15, kseg = (lane >> 4) * 8;
  const unsigned short* Ap = A + (size_t)(mbase + l15)*K + kseg;
  const unsigned short* Wp0; const unsigned short* Wp1;
  const unsigned short* Wp2; const unsigned short* Wp3;
  {
    int c0 = nbase + 0*16 + l15; if (c0 >= N) c0 = N-1;
    int c1 = nbase + 1*16 + l15; if (c1 >= N) c1 = N-1;
    int c2 = nbase + 2*16 + l15; if (c2 >= N) c2 = N-1;
    int c3 = nbase + 3*16 + l15; if (c3 >= N) c3 = N-1;
    Wp0 = W + (size_t)c0*K + kseg; Wp1 = W + (size_t)c1*K + kseg;
    Wp2 = W + (size_t)c2*K + kseg; Wp3 = W + (size_t)c3*K + kseg;
  }
  f32x4 acc0 = {0.f,0.f,0.f,0.f}, acc1 = {0.f,0.f,0.f,0.f};
  f32x4 acc2 = {0.f,0.f,0.f,0.f}, acc3 = {0.f,0.f,0.f,0.f};
  #pragma unroll 2
  for (int k = 0; k < K; k += 32){
    bf16x8 a  = *reinterpret_cast<const bf16x8*>(Ap  + k);
    bf16x8 b0 = *reinterpret_cast<const bf16x8*>(Wp0 + k);
    bf16x8 b1 = *reinterpret_cast<const bf16x8*>(Wp1 + k);
    bf16x8 b2 = *reinterpret_cast<const bf16x8*>(Wp2 + k);
    bf16x8 b3 = *reinterpret_cast<const bf16x8*>(Wp3 + k);
    acc0 = __builtin_amdgcn_mfma_f32_16x16x32_bf16(a, b0, acc0, 0,0,0);
    acc1 = __builtin_amdgcn_mfma_f32_16x16x32_bf16(a, b1, acc1, 0,0,0);
    acc2 = __builtin_amdgcn_mfma_f32_16x16x32_bf16(a, b2, acc2, 0,0,0);
    acc3 = __builtin_amdgcn_mfma_f32_16x16x32_bf16(a, b3, acc3, 0,0,0);
  }
  int rbase = mbase + (lane >> 4)*4;
  f32x4 accs[4] = {acc0, acc1, acc2, acc3};
  #pragma unroll
  for (int f=0; f<4; f++){
    int col = nbase + f*16 + l15;
    if (col < N){
      #pragma unroll
      for (int j=0; j<4; j++){
        size_t idx = (size_t)(rbase + j)*N + col;
        if (OUTMODE == 0)      ((float*)Cout)[idx] = accs[f][j];
        else if (OUTMODE == 1) ((unsigned short*)Cout)[idx] = f2bf(accs[f][j]);
        else                   ((float*)Cout)[idx] += accs[f][j];
      }
    }
  }
}

// ---------------- depthwise causal conv(4) + bias + SiLU: xz[:, :512] -> u bf16 ----------------
__global__ void conv_kernel(const unsigned short* __restrict__ xz, const float* __restrict__ cw,
                            const float* __restrict__ cb, unsigned short* __restrict__ u){
  size_t idx = (size_t)blockIdx.x*256 + threadIdx.x;  // over MROWS*512
  int d = (int)(idx & 511);
  size_t row = idx >> 9;
  int l = (int)(row & (SEQ-1));
  float w0 = cw[d*4+0], w1 = cw[d*4+1], w2 = cw[d*4+2], w3 = cw[d*4+3];
  float acc = cb[d];
  const unsigned short* base = xz + row*1024 + d;
  acc += bf2f(base[0]) * w3;
  if (l >= 1) acc += bf2f(*(base - 1024)) * w2;
  if (l >= 2) acc += bf2f(*(base - 2048)) * w1;
  if (l >= 3) acc += bf2f(*(base - 3072)) * w0;
  float s = acc / (1.f + expf(-acc));
  u[row*512 + d] = f2bf(s);
}

// ---------------- delta = softplus(dt @ W_dt^T + b_dt), bf16 out ----------------
__global__ void delta_kernel(const float* __restrict__ xdb, const float* __restrict__ Wdt,
                             const float* __restrict__ bdt, unsigned short* __restrict__ delta){
  __shared__ float sdt[16];
  size_t row = blockIdx.x;
  int d = threadIdx.x;  // 512 threads
  if (d < 16) sdt[d] = xdb[row*48 + d];
  __syncthreads();
  f32x4 w0 = *reinterpret_cast<const f32x4*>(Wdt + d*16 + 0);
  f32x4 w1 = *reinterpret_cast<const f32x4*>(Wdt + d*16 + 4);
  f32x4 w2 = *reinterpret_cast<const f32x4*>(Wdt + d*16 + 8);
  f32x4 w3 = *reinterpret_cast<const f32x4*>(Wdt + d*16 + 12);
  float acc = bdt[d];
  acc += sdt[0]*w0.x + sdt[1]*w0.y + sdt[2]*w0.z + sdt[3]*w0.w;
  acc += sdt[4]*w1.x + sdt[5]*w1.y + sdt[6]*w1.z + sdt[7]*w1.w;
  acc += sdt[8]*w2.x + sdt[9]*w2.y + sdt[10]*w2.z + sdt[11]*w2.w;
  acc += sdt[12]*w3.x + sdt[13]*w3.y + sdt[14]*w3.z + sdt[15]*w3.w;
  float sp = (acc > 20.f) ? acc : log1pf(expf(acc));
  delta[row*512 + d] = f2bf(sp);
}

// ---------------- SSM chunked scan ----------------
// block = (b, cg, c): 256 threads; thread t -> d = cg*16 + t/16... (wave layout below)
// pass1: local scan from h=0 over CL steps; store A_prod (=exp(A*sum_dv)) and h_final (bf16)
__global__ void __launch_bounds__(256) scan_pass1(
    const unsigned short* __restrict__ delta, const unsigned short* __restrict__ u,
    const float* __restrict__ xdb, const float* __restrict__ Alog,
    unsigned short* __restrict__ Abuf, unsigned short* __restrict__ Hbuf){
  int wave = threadIdx.x >> 6, lane = threadIdx.x & 63;
  int n = lane & 15;
  int cloc = (wave << 2) | (lane >> 4);
  int bid = blockIdx.x;
  int c   = bid & (CCH-1);
  int cg  = (bid >> 5) & 31;
  int b   = bid >> 10;
  int d   = cg*16 + cloc;
  float A = -expf(Alog[d*16 + n]);
  float h = 0.f, sumdv = 0.f;
  size_t rowbase = (size_t)b*SEQ + (size_t)c*CL;
  const unsigned short* dptr = delta + rowbase*512 + d;
  const unsigned short* uptr = u     + rowbase*512 + d;
  const float*          bptr = xdb   + rowbase*48 + 16 + n;
  #pragma unroll 8
  for (int l=0; l<CL; l++){
    float dv = bf2f(dptr[(size_t)l*512]);
    float uv = bf2f(uptr[(size_t)l*512]);
    float bm = bptr[(size_t)l*48];
    float a = __expf(dv * A);
    h = a*h + (dv*uv)*bm;
    sumdv += dv;
  }
  size_t o = (size_t)c*SC + ((size_t)(b*32 + cg) << 8) + threadIdx.x;
  Abuf[o] = f2bf(__expf(A * sumdv));
  Hbuf[o] = f2bf(h);
}

// pass2: serial prefix over the CCH chunks per (b,d,n); rewrite Hbuf[c] with h_init(c)
__global__ void __launch_bounds__(256) scan_pass2(
    const unsigned short* __restrict__ Abuf, unsigned short* __restrict__ Hbuf){
  int gid = blockIdx.x*256 + threadIdx.x;   // 0 .. SC-1
  float H = 0.f;
  #pragma unroll 8
  for (int c=0; c<CCH; c++){
    size_t o = (size_t)c*SC + gid;
    float a  = bf2f(Abuf[o]);
    float hf = bf2f(Hbuf[o]);
    Hbuf[o] = f2bf(H);          // h_init for chunk c
    H = a*H + hf;
  }
}

// pass3: re-run chunk from h_init, emit y = C.h + D*u (bf16)
__global__ void __launch_bounds__(256) scan_pass3(
    const unsigned short* __restrict__ delta, const unsigned short* __restrict__ u,
    const float* __restrict__ xdb, const float* __restrict__ Alog,
    const float* __restrict__ Dp, const unsigned short* __restrict__ Hbuf,
    unsigned short* __restrict__ y){
  int wave = threadIdx.x >> 6, lane = threadIdx.x & 63;
  int n = lane & 15;
  int cloc = (wave << 2) | (lane >> 4);
  int bid = blockIdx.x;
  int c   = bid & (CCH-1);
  int cg  = (bid >> 5) & 31;
  int b   = bid >> 10;
  int d   = cg*16 + cloc;
  float A  = -expf(Alog[d*16 + n]);
  float Dd = Dp[d];
  float h  = bf2f(Hbuf[(size_t)c*SC + ((size_t)(b*32 + cg) << 8) + threadIdx.x]);
  size_t rowbase = (size_t)b*SEQ + (size_t)c*CL;
  const unsigned short* dptr = delta + rowbase*512 + d;
  const unsigned short* uptr = u     + rowbase*512 + d;
  const float*          bptr = xdb   + rowbase*48 + 16 + n;
  const float*          cptr = xdb   + rowbase*48 + 32 + n;
  unsigned short*       yptr = y     + rowbase*512 + d;
  #pragma unroll 4
  for (int l=0; l<CL; l++){
    float dv = bf2f(dptr[(size_t)l*512]);
    float uv = bf2f(uptr[(size_t)l*512]);
    float bm = bptr[(size_t)l*48];
    float cm = cptr[(size_t)l*48];
    float a = __expf(dv * A);
    h = a*h + (dv*uv)*bm;
    float p = h * cm;
    p += __shfl_xor(p, 1, 64);
    p += __shfl_xor(p, 2, 64);
    p += __shfl_xor(p, 4, 64);
    p += __shfl_xor(p, 8, 64);
    if (n == 0) yptr[(size_t)l*512] = f2bf(p + Dd*uv);
  }
}

// ---------------- gate: g = y * silu(z), write bf16 over u buffer ----------------
__global__ void gate_kernel(const unsigned short* __restrict__ y, const unsigned short* __restrict__ xz,
                            unsigned short* __restrict__ g){
  size_t idx = (size_t)blockIdx.x*256 + threadIdx.x;
  size_t row = idx >> 9; int d = (int)(idx & 511);
  float z = bf2f(xz[row*1024 + 512 + d]);
  float gv = bf2f(y[idx]) * (z / (1.f + expf(-z)));
  g[idx] = f2bf(gv);
}

extern "C" void kernel_launch(void* const* d_in, const int* in_sizes, int n_in,
                              void* d_out, int out_size, void* d_ws, size_t ws_size,
                              hipStream_t stream){
  (void)in_sizes; (void)n_in; (void)out_size; (void)ws_size;
  const float* x      = (const float*)d_in[0];
  const float* W_in   = (const float*)d_in[1];
  const float* conv_w = (const float*)d_in[2];
  const float* conv_b = (const float*)d_in[3];
  const float* W_x    = (const float*)d_in[4];
  const float* W_dt   = (const float*)d_in[5];
  const float* b_dt   = (const float*)d_in[6];
  const float* A_log  = (const float*)d_in[7];
  const float* Dp     = (const float*)d_in[8];
  const float* W_out  = (const float*)d_in[9];
  const float* ln_g   = (const float*)d_in[10];
  const float* ln_b   = (const float*)d_in[11];
  float* out = (float*)d_out;

  // workspace carve-up (~187.5 MB total; y lives in d_out)
  char* p = (char*)d_ws;
  auto alloc = [&](size_t bytes)->char*{
    char* r = p; p += (bytes + 255) & ~(size_t)255; return r;
  };
  float*          hbuf   = (float*)alloc((size_t)MROWS*DM*4);           // 33.5 MB residual f32
  unsigned short* xzb    = (unsigned short*)alloc((size_t)MROWS*1024*2);// 67 MB
  unsigned short* ubuf   = (unsigned short*)alloc((size_t)MROWS*DI*2);  // 33.5 MB
  unsigned short* lnb    = (unsigned short*)alloc((size_t)MROWS*DI*2);  // 33.5 MB shared: lnb [M,256] / delta [M,512]
  unsigned short* dlt    = lnb;                                         // alias (disjoint live ranges)
  float*          xdb    = (float*)alloc((size_t)MROWS*48*4);           // 6.3 MB
  unsigned short* WinB   = (unsigned short*)alloc((size_t)NL*1024*DM*2);// 3.1 MB
  unsigned short* WxB    = (unsigned short*)alloc((size_t)NL*48*DI*2);  // 0.3 MB
  unsigned short* WoutB  = (unsigned short*)alloc((size_t)NL*DM*DI*2);  // 1.6 MB
  unsigned short* Abuf   = (unsigned short*)alloc((size_t)CCH*SC*2);    // 4.2 MB
  unsigned short* Hbuf   = (unsigned short*)alloc((size_t)CCH*SC*2);    // 4.2 MB
  unsigned short* ybuf   = (unsigned short*)d_out;                      // 33.5 MB scratch in d_out

  // weight conversion
  {
    int n1 = NL*1024*DM;  cvt_bf16<<<(n1+255)/256, 256, 0, stream>>>(W_in,  WinB,  n1);
    int n2 = NL*48*DI;    cvt_bf16<<<(n2+255)/256, 256, 0, stream>>>(W_x,   WxB,   n2);
    int n3 = NL*DM*DI;    cvt_bf16<<<(n3+255)/256, 256, 0, stream>>>(W_out, WoutB, n3);
  }

  transpose_in<<<dim3(SEQ/32, DM/32, BATCH), dim3(32,8), 0, stream>>>(x, hbuf);

  for (int i=0; i<NL; i++){
    const unsigned short* Wi = WinB  + (size_t)i*1024*DM;
    const unsigned short* Wx = WxB   + (size_t)i*48*DI;
    const unsigned short* Wo = WoutB + (size_t)i*DM*DI;

    ln_kernel<<<MROWS/4, 256, 0, stream>>>(hbuf, ln_g + i*DM, ln_b + i*DM, lnb);

    // xz = ln @ W_in^T  [M,1024] bf16
    gemm_kernel<1><<<dim3(1024/64, MROWS/64), 256, 0, stream>>>(lnb, Wi, xzb, 1024, DM);

    conv_kernel<<<(size_t)MROWS*DI/256, 256, 0, stream>>>(xzb, conv_w + (size_t)i*DI*4,
                                                          conv_b + i*DI, ubuf);

    // xdb = u @ W_x^T  [M,48] f32
    gemm_kernel<0><<<dim3(1, MROWS/64), 256, 0, stream>>>(ubuf, Wx, xdb, 48, DI);

    delta_kernel<<<MROWS, 512, 0, stream>>>(xdb, W_dt + (size_t)i*DI*DTR, b_dt + i*DI, dlt);

    scan_pass1<<<BATCH*32*CCH, 256, 0, stream>>>(dlt, ubuf, xdb,
                                                 A_log + (size_t)i*DI*DS, Abuf, Hbuf);
    scan_pass2<<<SC/256, 256, 0, stream>>>(Abuf, Hbuf);
    scan_pass3<<<BATCH*32*CCH, 256, 0, stream>>>(dlt, ubuf, xdb,
                                                 A_log + (size_t)i*DI*DS, Dp + i*DI, Hbuf, ybuf);

    gate_kernel<<<(size_t)MROWS*DI/256, 256, 0, stream>>>(ybuf, xzb, ubuf);

    // h += g @ W_out^T  [M,256] f32 accumulate
    gemm_kernel<2><<<dim3(DM/64, MROWS/64), 256, 0, stream>>>(ubuf, Wo, hbuf, DM, DI);
  }

  transpose_out<<<dim3(SEQ/32, DM/32, BATCH), dim3(32,8), 0, stream>>>(hbuf, out);
}

// Round 4
// 2952.833 us; speedup vs baseline: 4.3908x; 1.5438x over previous
//
#include <hip/hip_runtime.h>

#define BATCH 8
#define SEQ   4096
#define DM    256
#define DI    512
#define DS    16
#define DTR   16
#define NL    6
#define MROWS (BATCH*SEQ)   // 32768
#define CCH   64            // scan chunks
#define CL    (SEQ/CCH)     // 64 steps per chunk
#define SC    (BATCH*DI*DS) // 65536 per-chunk scan states

typedef float  f32x4 __attribute__((ext_vector_type(4)));
typedef __bf16 bf16x8 __attribute__((ext_vector_type(8)));

__device__ __forceinline__ float bf2f(unsigned short b){
  unsigned u = ((unsigned)b) << 16;
  return __builtin_bit_cast(float, u);
}
__device__ __forceinline__ unsigned short f2bf(float f){
  unsigned u = __builtin_bit_cast(unsigned, f);
  unsigned r = u + 0x7FFFu + ((u >> 16) & 1u);
  return (unsigned short)(r >> 16);
}

#define ASEL(i) ((i)<4?Aq0[(i)&3]:(i)<8?Aq1[(i)&3]:(i)<12?Aq2[(i)&3]:Aq3[(i)&3])
#define BSEL(i) ((i)<4?B0[(i)&3]:(i)<8?B1[(i)&3]:(i)<12?B2[(i)&3]:B3[(i)&3])
#define CSEL(i) ((i)<4?C0[(i)&3]:(i)<8?C1[(i)&3]:(i)<12?C2[(i)&3]:C3[(i)&3])

// ---------------- transpose x [B,256,L] f32 -> h [(b*L+l)*256+c] f32 ----------------
__global__ void transpose_in(const float* __restrict__ x, float* __restrict__ h){
  __shared__ float tile[32][33];
  int b = blockIdx.z;
  int l0 = blockIdx.x*32, c0 = blockIdx.y*32;
  int tx = threadIdx.x, ty = threadIdx.y;
  #pragma unroll
  for (int i=0;i<4;i++)
    tile[ty+8*i][tx] = x[((size_t)(b*DM + c0+ty+8*i))*SEQ + l0 + tx];
  __syncthreads();
  #pragma unroll
  for (int i=0;i<4;i++)
    h[((size_t)(b*SEQ + l0+ty+8*i))*DM + c0 + tx] = tile[tx][ty+8*i];
}

// ---------------- transpose h -> out [B,256,L] ----------------
__global__ void transpose_out(const float* __restrict__ h, float* __restrict__ out){
  __shared__ float tile[32][33];
  int b = blockIdx.z;
  int l0 = blockIdx.x*32, c0 = blockIdx.y*32;
  int tx = threadIdx.x, ty = threadIdx.y;
  #pragma unroll
  for (int i=0;i<4;i++)
    tile[ty+8*i][tx] = h[((size_t)(b*SEQ + l0+ty+8*i))*DM + c0 + tx];
  __syncthreads();
  #pragma unroll
  for (int i=0;i<4;i++)
    out[((size_t)(b*DM + c0+ty+8*i))*SEQ + l0 + tx] = tile[tx][ty+8*i];
}

// ---------------- f32 -> bf16 convert ----------------
__global__ void cvt_bf16(const float* __restrict__ in, unsigned short* __restrict__ out, int n){
  int i = blockIdx.x*256 + threadIdx.x;
  if (i < n) out[i] = f2bf(in[i]);
}

// ---------------- LayerNorm over 256 channels, one wave per row, bf16 out ----------------
__global__ void ln_kernel(const float* __restrict__ h, const float* __restrict__ g,
                          const float* __restrict__ bta, unsigned short* __restrict__ out){
  int wave = threadIdx.x >> 6, lane = threadIdx.x & 63;
  size_t row = (size_t)blockIdx.x*4 + wave;
  const float* hr = h + row*DM;
  f32x4 v = *reinterpret_cast<const f32x4*>(hr + lane*4);
  float s  = v.x + v.y + v.z + v.w;
  float sq = v.x*v.x + v.y*v.y + v.z*v.z + v.w*v.w;
  #pragma unroll
  for (int off=32; off; off>>=1){
    s  += __shfl_xor(s,  off, 64);
    sq += __shfl_xor(sq, off, 64);
  }
  float mean = s * (1.f/DM);
  float var  = sq * (1.f/DM) - mean*mean;
  float rstd = rsqrtf(var + 1e-5f);
  f32x4 gg = *reinterpret_cast<const f32x4*>(g   + lane*4);
  f32x4 bb = *reinterpret_cast<const f32x4*>(bta + lane*4);
  unsigned short* o = out + row*DM + lane*4;
  o[0] = f2bf((v.x-mean)*rstd*gg.x + bb.x);
  o[1] = f2bf((v.y-mean)*rstd*gg.y + bb.y);
  o[2] = f2bf((v.z-mean)*rstd*gg.z + bb.z);
  o[3] = f2bf((v.w-mean)*rstd*gg.w + bb.w);
}

// ---------------- bf16 MFMA GEMM: C[M,N] = A[M,K] @ W[N,K]^T ----------------
// OUTMODE 0: f32 store, 1: bf16 store, 2: f32 accumulate (C += )
template<int OUTMODE>
__global__ void gemm_kernel(const unsigned short* __restrict__ A,
                            const unsigned short* __restrict__ W,
                            void* __restrict__ Cout, int N, int K){
  int wave = threadIdx.x >> 6, lane = threadIdx.x & 63;
  int mbase = blockIdx.y*64 + wave*16;
  int nbase = blockIdx.x*64;
  int l15 = lane & 15, kseg = (lane >> 4) * 8;
  const unsigned short* Ap = A + (size_t)(mbase + l15)*K + kseg;
  const unsigned short* Wp0; const unsigned short* Wp1;
  const unsigned short* Wp2; const unsigned short* Wp3;
  {
    int c0 = nbase + 0*16 + l15; if (c0 >= N) c0 = N-1;
    int c1 = nbase + 1*16 + l15; if (c1 >= N) c1 = N-1;
    int c2 = nbase + 2*16 + l15; if (c2 >= N) c2 = N-1;
    int c3 = nbase + 3*16 + l15; if (c3 >= N) c3 = N-1;
    Wp0 = W + (size_t)c0*K + kseg; Wp1 = W + (size_t)c1*K + kseg;
    Wp2 = W + (size_t)c2*K + kseg; Wp3 = W + (size_t)c3*K + kseg;
  }
  f32x4 acc0 = {0.f,0.f,0.f,0.f}, acc1 = {0.f,0.f,0.f,0.f};
  f32x4 acc2 = {0.f,0.f,0.f,0.f}, acc3 = {0.f,0.f,0.f,0.f};
  #pragma unroll 2
  for (int k = 0; k < K; k += 32){
    bf16x8 a  = *reinterpret_cast<const bf16x8*>(Ap  + k);
    bf16x8 b0 = *reinterpret_cast<const bf16x8*>(Wp0 + k);
    bf16x8 b1 = *reinterpret_cast<const bf16x8*>(Wp1 + k);
    bf16x8 b2 = *reinterpret_cast<const bf16x8*>(Wp2 + k);
    bf16x8 b3 = *reinterpret_cast<const bf16x8*>(Wp3 + k);
    acc0 = __builtin_amdgcn_mfma_f32_16x16x32_bf16(a, b0, acc0, 0,0,0);
    acc1 = __builtin_amdgcn_mfma_f32_16x16x32_bf16(a, b1, acc1, 0,0,0);
    acc2 = __builtin_amdgcn_mfma_f32_16x16x32_bf16(a, b2, acc2, 0,0,0);
    acc3 = __builtin_amdgcn_mfma_f32_16x16x32_bf16(a, b3, acc3, 0,0,0);
  }
  int rbase = mbase + (lane >> 4)*4;
  f32x4 accs[4] = {acc0, acc1, acc2, acc3};
  #pragma unroll
  for (int f=0; f<4; f++){
    int col = nbase + f*16 + l15;
    if (col < N){
      #pragma unroll
      for (int j=0; j<4; j++){
        size_t idx = (size_t)(rbase + j)*N + col;
        if (OUTMODE == 0)      ((float*)Cout)[idx] = accs[f][j];
        else if (OUTMODE == 1) ((unsigned short*)Cout)[idx] = f2bf(accs[f][j]);
        else                   ((float*)Cout)[idx] += accs[f][j];
      }
    }
  }
}

// ---------------- depthwise causal conv(4) + bias + SiLU: xz[:, :512] -> u bf16 ----------------
__global__ void conv_kernel(const unsigned short* __restrict__ xz, const float* __restrict__ cw,
                            const float* __restrict__ cb, unsigned short* __restrict__ u){
  size_t idx = (size_t)blockIdx.x*256 + threadIdx.x;  // over MROWS*512
  int d = (int)(idx & 511);
  size_t row = idx >> 9;
  int l = (int)(row & (SEQ-1));
  float w0 = cw[d*4+0], w1 = cw[d*4+1], w2 = cw[d*4+2], w3 = cw[d*4+3];
  float acc = cb[d];
  const unsigned short* base = xz + row*1024 + d;
  acc += bf2f(base[0]) * w3;
  if (l >= 1) acc += bf2f(*(base - 1024)) * w2;
  if (l >= 2) acc += bf2f(*(base - 2048)) * w1;
  if (l >= 3) acc += bf2f(*(base - 3072)) * w0;
  float s = acc / (1.f + expf(-acc));
  u[row*512 + d] = f2bf(s);
}

// ---------------- delta = softplus(dt @ W_dt^T + b_dt), bf16 out ----------------
__global__ void delta_kernel(const float* __restrict__ xdb, const float* __restrict__ Wdt,
                             const float* __restrict__ bdt, unsigned short* __restrict__ delta){
  __shared__ float sdt[16];
  size_t row = blockIdx.x;
  int d = threadIdx.x;  // 512 threads
  if (d < 16) sdt[d] = xdb[row*48 + d];
  __syncthreads();
  f32x4 w0 = *reinterpret_cast<const f32x4*>(Wdt + d*16 + 0);
  f32x4 w1 = *reinterpret_cast<const f32x4*>(Wdt + d*16 + 4);
  f32x4 w2 = *reinterpret_cast<const f32x4*>(Wdt + d*16 + 8);
  f32x4 w3 = *reinterpret_cast<const f32x4*>(Wdt + d*16 + 12);
  float acc = bdt[d];
  acc += sdt[0]*w0.x + sdt[1]*w0.y + sdt[2]*w0.z + sdt[3]*w0.w;
  acc += sdt[4]*w1.x + sdt[5]*w1.y + sdt[6]*w1.z + sdt[7]*w1.w;
  acc += sdt[8]*w2.x + sdt[9]*w2.y + sdt[10]*w2.z + sdt[11]*w2.w;
  acc += sdt[12]*w3.x + sdt[13]*w3.y + sdt[14]*w3.z + sdt[15]*w3.w;
  float sp = (acc > 20.f) ? acc : log1pf(expf(acc));
  delta[row*512 + d] = f2bf(sp);
}

// ================= SSM chunked scan, lane-per-d layout =================
// pass1: local scan from h=0; store sumdv (f32) and h_final[16] (f32)
template<bool POW>
__device__ __forceinline__ void pass1_body(
    const unsigned short* dptr, const unsigned short* uptr, const float* bptr,
    const float* A, float* h, float& sumdv){
  #pragma unroll 2
  for (int l=0; l<CL; l++){
    float dv = bf2f(dptr[(size_t)l*512]);
    float uv = bf2f(uptr[(size_t)l*512]);
    const float* br = bptr + (size_t)l*48;
    f32x4 B0 = *(const f32x4*)(br + 0);
    f32x4 B1 = *(const f32x4*)(br + 4);
    f32x4 B2 = *(const f32x4*)(br + 8);
    f32x4 B3 = *(const f32x4*)(br + 12);
    float t = dv*uv;
    sumdv += dv;
    if (POW){
      float a0 = __expf(dv*A[0]);
      float ap = 1.f;
      #pragma unroll
      for (int i=0;i<16;i++){ ap *= a0; h[i] = ap*h[i] + t*BSEL(i); }
    } else {
      #pragma unroll
      for (int i=0;i<16;i++){ float a = __expf(dv*A[i]); h[i] = a*h[i] + t*BSEL(i); }
    }
  }
}

__global__ void __launch_bounds__(256) scan_pass1(
    const unsigned short* __restrict__ dlt, const unsigned short* __restrict__ u,
    const float* __restrict__ xdb, const float* __restrict__ Alog,
    float* __restrict__ sumdvB, float* __restrict__ Hbuf){
  int bid = blockIdx.x;               // ((b*CCH)+c)*2 + half
  int half = bid & 1;
  int c = (bid >> 1) & (CCH-1);
  int b = bid >> 7;
  int wave = threadIdx.x >> 6, lane = threadIdx.x & 63;
  int d = half*256 + wave*64 + lane;
  const float* ar = Alog + d*16;
  f32x4 Aq0 = *(const f32x4*)(ar+0), Aq1 = *(const f32x4*)(ar+4);
  f32x4 Aq2 = *(const f32x4*)(ar+8), Aq3 = *(const f32x4*)(ar+12);
  float A[16];
  #pragma unroll
  for (int i=0;i<16;i++) A[i] = -__expf(ASEL(i));
  bool pw = true;
  #pragma unroll
  for (int i=1;i<16;i++) pw = pw && (fabsf(A[i] - (float)(i+1)*A[0]) <= 1e-3f*fabsf(A[i]));
  float h[16];
  #pragma unroll
  for (int i=0;i<16;i++) h[i] = 0.f;
  float sumdv = 0.f;
  size_t rowbase = (size_t)b*SEQ + (size_t)c*CL;
  const unsigned short* dptr = dlt + rowbase*512 + d;
  const unsigned short* uptr = u   + rowbase*512 + d;
  const float*          bptr = xdb + rowbase*48 + 16;
  if (pw) pass1_body<true >(dptr, uptr, bptr, A, h, sumdv);
  else    pass1_body<false>(dptr, uptr, bptr, A, h, sumdv);
  size_t o = (size_t)(c*BATCH + b)*512 + d;
  sumdvB[o] = sumdv;
  float* Hp = Hbuf + o*16;
  *(f32x4*)(Hp+ 0) = f32x4{h[0],h[1],h[2],h[3]};
  *(f32x4*)(Hp+ 4) = f32x4{h[4],h[5],h[6],h[7]};
  *(f32x4*)(Hp+ 8) = f32x4{h[8],h[9],h[10],h[11]};
  *(f32x4*)(Hp+12) = f32x4{h[12],h[13],h[14],h[15]};
}

// pass2: thread per (b,d,n): serial combine over chunks; Hbuf[c] := h_init(c)
__global__ void __launch_bounds__(256) scan_pass2(
    const float* __restrict__ sumdvB, const float* __restrict__ Alog,
    float* __restrict__ Hbuf){
  int gid = blockIdx.x*256 + threadIdx.x;   // b*8192 + d*16 + n
  float A = -__expf(Alog[gid & 8191]);
  float H = 0.f;
  for (int c=0; c<CCH; c++){
    float s  = sumdvB[(size_t)c*(BATCH*DI) + (gid>>4)];
    size_t o = (size_t)c*SC + gid;
    float hf = Hbuf[o];
    Hbuf[o] = H;
    H = __expf(A*s)*H + hf;
  }
}

// pass3: re-run chunk from h_init; y = C.h + D*u; fused gate: g = y*silu(z); bf16 g over u
template<bool POW>
__device__ __forceinline__ void pass3_body(
    const unsigned short* dptr, unsigned short* uptr, const unsigned short* zptr,
    const float* bptr, const float* A, float* h, float Dd){
  #pragma unroll 2
  for (int l=0; l<CL; l++){
    float dv = bf2f(dptr[(size_t)l*512]);
    float uv = bf2f(uptr[(size_t)l*512]);
    float zv = bf2f(zptr[(size_t)l*1024]);
    const float* br = bptr + (size_t)l*48;
    f32x4 B0 = *(const f32x4*)(br + 0);
    f32x4 B1 = *(const f32x4*)(br + 4);
    f32x4 B2 = *(const f32x4*)(br + 8);
    f32x4 B3 = *(const f32x4*)(br + 12);
    f32x4 C0 = *(const f32x4*)(br + 16);
    f32x4 C1 = *(const f32x4*)(br + 20);
    f32x4 C2 = *(const f32x4*)(br + 24);
    f32x4 C3 = *(const f32x4*)(br + 28);
    float t = dv*uv;
    float p0=0.f,p1=0.f,p2=0.f,p3=0.f;
    if (POW){
      float a0 = __expf(dv*A[0]);
      float ap = 1.f;
      #pragma unroll
      for (int i=0;i<16;i++){
        ap *= a0;
        h[i] = ap*h[i] + t*BSEL(i);
        float hp = h[i]*CSEL(i);
        if ((i&3)==0) p0 += hp; else if ((i&3)==1) p1 += hp; else if ((i&3)==2) p2 += hp; else p3 += hp;
      }
    } else {
      #pragma unroll
      for (int i=0;i<16;i++){
        float a = __expf(dv*A[i]);
        h[i] = a*h[i] + t*BSEL(i);
        float hp = h[i]*CSEL(i);
        if ((i&3)==0) p0 += hp; else if ((i&3)==1) p1 += hp; else if ((i&3)==2) p2 += hp; else p3 += hp;
      }
    }
    float y = (p0+p1) + (p2+p3) + Dd*uv;
    float g = y * (zv / (1.f + __expf(-zv)));
    uptr[(size_t)l*512] = f2bf(g);
  }
}

__global__ void __launch_bounds__(256) scan_pass3(
    const unsigned short* __restrict__ dlt, unsigned short* __restrict__ u,
    const unsigned short* __restrict__ xz, const float* __restrict__ xdb,
    const float* __restrict__ Alog, const float* __restrict__ Dp,
    const float* __restrict__ Hbuf){
  int bid = blockIdx.x;
  int half = bid & 1;
  int c = (bid >> 1) & (CCH-1);
  int b = bid >> 7;
  int wave = threadIdx.x >> 6, lane = threadIdx.x & 63;
  int d = half*256 + wave*64 + lane;
  const float* ar = Alog + d*16;
  f32x4 Aq0 = *(const f32x4*)(ar+0), Aq1 = *(const f32x4*)(ar+4);
  f32x4 Aq2 = *(const f32x4*)(ar+8), Aq3 = *(const f32x4*)(ar+12);
  float A[16];
  #pragma unroll
  for (int i=0;i<16;i++) A[i] = -__expf(ASEL(i));
  bool pw = true;
  #pragma unroll
  for (int i=1;i<16;i++) pw = pw && (fabsf(A[i] - (float)(i+1)*A[0]) <= 1e-3f*fabsf(A[i]));
  float Dd = Dp[d];
  size_t o = (size_t)(c*BATCH + b)*512 + d;
  const float* Hp = Hbuf + o*16;
  f32x4 h0 = *(const f32x4*)(Hp+0), h1 = *(const f32x4*)(Hp+4);
  f32x4 h2 = *(const f32x4*)(Hp+8), h3 = *(const f32x4*)(Hp+12);
  float h[16] = {h0.x,h0.y,h0.z,h0.w, h1.x,h1.y,h1.z,h1.w,
                 h2.x,h2.y,h2.z,h2.w, h3.x,h3.y,h3.z,h3.w};
  size_t rowbase = (size_t)b*SEQ + (size_t)c*CL;
  const unsigned short* dptr = dlt + rowbase*512 + d;
  unsigned short*       uptr = u   + rowbase*512 + d;
  const unsigned short* zptr = xz  + rowbase*1024 + 512 + d;
  const float*          bptr = xdb + rowbase*48 + 16;
  if (pw) pass3_body<true >(dptr, uptr, zptr, bptr, A, h, Dd);
  else    pass3_body<false>(dptr, uptr, zptr, bptr, A, h, Dd);
}

extern "C" void kernel_launch(void* const* d_in, const int* in_sizes, int n_in,
                              void* d_out, int out_size, void* d_ws, size_t ws_size,
                              hipStream_t stream){
  (void)in_sizes; (void)n_in; (void)out_size; (void)ws_size;
  const float* x      = (const float*)d_in[0];
  const float* W_in   = (const float*)d_in[1];
  const float* conv_w = (const float*)d_in[2];
  const float* conv_b = (const float*)d_in[3];
  const float* W_x    = (const float*)d_in[4];
  const float* W_dt   = (const float*)d_in[5];
  const float* b_dt   = (const float*)d_in[6];
  const float* A_log  = (const float*)d_in[7];
  const float* Dp     = (const float*)d_in[8];
  const float* W_out  = (const float*)d_in[9];
  const float* ln_g   = (const float*)d_in[10];
  const float* ln_b   = (const float*)d_in[11];
  float* out = (float*)d_out;

  // workspace carve-up (~198 MB)
  char* p = (char*)d_ws;
  auto alloc = [&](size_t bytes)->char*{
    char* r = p; p += (bytes + 255) & ~(size_t)255; return r;
  };
  float*          hbuf   = (float*)alloc((size_t)MROWS*DM*4);           // 33.5 MB residual f32
  unsigned short* xzb    = (unsigned short*)alloc((size_t)MROWS*1024*2);// 67 MB
  unsigned short* ubuf   = (unsigned short*)alloc((size_t)MROWS*DI*2);  // 33.5 MB (u, then gated g)
  unsigned short* lnb    = (unsigned short*)alloc((size_t)MROWS*DI*2);  // 33.5 MB shared: lnb / delta
  unsigned short* dlt    = lnb;                                         // alias (disjoint live ranges)
  float*          xdb    = (float*)alloc((size_t)MROWS*48*4);           // 6.3 MB
  unsigned short* WinB   = (unsigned short*)alloc((size_t)NL*1024*DM*2);// 3.1 MB
  unsigned short* WxB    = (unsigned short*)alloc((size_t)NL*48*DI*2);  // 0.3 MB
  unsigned short* WoutB  = (unsigned short*)alloc((size_t)NL*DM*DI*2);  // 1.6 MB
  float*          sumdvB = (float*)alloc((size_t)CCH*BATCH*DI*4);       // 1.05 MB
  float*          Hbuf   = (float*)alloc((size_t)CCH*SC*4);             // 16.8 MB

  // weight conversion
  {
    int n1 = NL*1024*DM;  cvt_bf16<<<(n1+255)/256, 256, 0, stream>>>(W_in,  WinB,  n1);
    int n2 = NL*48*DI;    cvt_bf16<<<(n2+255)/256, 256, 0, stream>>>(W_x,   WxB,   n2);
    int n3 = NL*DM*DI;    cvt_bf16<<<(n3+255)/256, 256, 0, stream>>>(W_out, WoutB, n3);
  }

  transpose_in<<<dim3(SEQ/32, DM/32, BATCH), dim3(32,8), 0, stream>>>(x, hbuf);

  for (int i=0; i<NL; i++){
    const unsigned short* Wi = WinB  + (size_t)i*1024*DM;
    const unsigned short* Wx = WxB   + (size_t)i*48*DI;
    const unsigned short* Wo = WoutB + (size_t)i*DM*DI;
    const float* Al = A_log + (size_t)i*DI*DS;

    ln_kernel<<<MROWS/4, 256, 0, stream>>>(hbuf, ln_g + i*DM, ln_b + i*DM, lnb);

    // xz = ln @ W_in^T  [M,1024] bf16
    gemm_kernel<1><<<dim3(1024/64, MROWS/64), 256, 0, stream>>>(lnb, Wi, xzb, 1024, DM);

    conv_kernel<<<(size_t)MROWS*DI/256, 256, 0, stream>>>(xzb, conv_w + (size_t)i*DI*4,
                                                          conv_b + i*DI, ubuf);

    // xdb = u @ W_x^T  [M,48] f32
    gemm_kernel<0><<<dim3(1, MROWS/64), 256, 0, stream>>>(ubuf, Wx, xdb, 48, DI);

    delta_kernel<<<MROWS, 512, 0, stream>>>(xdb, W_dt + (size_t)i*DI*DTR, b_dt + i*DI, dlt);

    scan_pass1<<<BATCH*CCH*2, 256, 0, stream>>>(dlt, ubuf, xdb, Al, sumdvB, Hbuf);
    scan_pass2<<<SC/256, 256, 0, stream>>>(sumdvB, Al, Hbuf);
    scan_pass3<<<BATCH*CCH*2, 256, 0, stream>>>(dlt, ubuf, xzb, xdb, Al, Dp + i*DI, Hbuf);

    // h += g @ W_out^T  [M,256] f32 accumulate
    gemm_kernel<2><<<dim3(DM/64, MROWS/64), 256, 0, stream>>>(ubuf, Wo, hbuf, DM, DI);
  }

  transpose_out<<<dim3(SEQ/32, DM/32, BATCH), dim3(32,8), 0, stream>>>(hbuf, out);
}

// Round 5
// 2048.270 us; speedup vs baseline: 6.3299x; 1.4416x over previous
//
#include <hip/hip_runtime.h>

#define BATCH 8
#define SEQ   4096
#define DM    256
#define DI    512
#define DS    16
#define DTR   16
#define NL    6
#define MROWS (BATCH*SEQ)   // 32768
#define CCH   64            // scan chunks
#define CL    (SEQ/CCH)     // 64 steps per chunk
#define SC    (BATCH*DI*DS) // 65536 per-chunk scan states

typedef float  f32x4 __attribute__((ext_vector_type(4)));
typedef __bf16 bf16x8 __attribute__((ext_vector_type(8)));

__device__ __forceinline__ float bf2f(unsigned short b){
  unsigned u = ((unsigned)b) << 16;
  return __builtin_bit_cast(float, u);
}
__device__ __forceinline__ unsigned short f2bf(float f){
  unsigned u = __builtin_bit_cast(unsigned, f);
  unsigned r = u + 0x7FFFu + ((u >> 16) & 1u);
  return (unsigned short)(r >> 16);
}

#define ASEL(i) ((i)<4?Aq0[(i)&3]:(i)<8?Aq1[(i)&3]:(i)<12?Aq2[(i)&3]:Aq3[(i)&3])
#define BSEL(i) ((i)<4?B0[(i)&3]:(i)<8?B1[(i)&3]:(i)<12?B2[(i)&3]:B3[(i)&3])
#define CSEL(i) ((i)<4?C0[(i)&3]:(i)<8?C1[(i)&3]:(i)<12?C2[(i)&3]:C3[(i)&3])

// ---------------- transpose x [B,256,L] f32 -> h [(b*L+l)*256+c] f32 ----------------
__global__ void transpose_in(const float* __restrict__ x, float* __restrict__ h){
  __shared__ float tile[32][33];
  int b = blockIdx.z;
  int l0 = blockIdx.x*32, c0 = blockIdx.y*32;
  int tx = threadIdx.x, ty = threadIdx.y;
  #pragma unroll
  for (int i=0;i<4;i++)
    tile[ty+8*i][tx] = x[((size_t)(b*DM + c0+ty+8*i))*SEQ + l0 + tx];
  __syncthreads();
  #pragma unroll
  for (int i=0;i<4;i++)
    h[((size_t)(b*SEQ + l0+ty+8*i))*DM + c0 + tx] = tile[tx][ty+8*i];
}

// ---------------- transpose h -> out [B,256,L] ----------------
__global__ void transpose_out(const float* __restrict__ h, float* __restrict__ out){
  __shared__ float tile[32][33];
  int b = blockIdx.z;
  int l0 = blockIdx.x*32, c0 = blockIdx.y*32;
  int tx = threadIdx.x, ty = threadIdx.y;
  #pragma unroll
  for (int i=0;i<4;i++)
    tile[ty+8*i][tx] = h[((size_t)(b*SEQ + l0+ty+8*i))*DM + c0 + tx];
  __syncthreads();
  #pragma unroll
  for (int i=0;i<4;i++)
    out[((size_t)(b*DM + c0+ty+8*i))*SEQ + l0 + tx] = tile[tx][ty+8*i];
}

// ---------------- f32 -> bf16 convert ----------------
__global__ void cvt_bf16(const float* __restrict__ in, unsigned short* __restrict__ out, int n){
  int i = blockIdx.x*256 + threadIdx.x;
  if (i < n) out[i] = f2bf(in[i]);
}

// ---------------- LayerNorm over 256 channels, one wave per row, bf16 out ----------------
__global__ void ln_kernel(const float* __restrict__ h, const float* __restrict__ g,
                          const float* __restrict__ bta, unsigned short* __restrict__ out){
  int wave = threadIdx.x >> 6, lane = threadIdx.x & 63;
  size_t row = (size_t)blockIdx.x*4 + wave;
  const float* hr = h + row*DM;
  f32x4 v = *reinterpret_cast<const f32x4*>(hr + lane*4);
  float s  = v.x + v.y + v.z + v.w;
  float sq = v.x*v.x + v.y*v.y + v.z*v.z + v.w*v.w;
  #pragma unroll
  for (int off=32; off; off>>=1){
    s  += __shfl_xor(s,  off, 64);
    sq += __shfl_xor(sq, off, 64);
  }
  float mean = s * (1.f/DM);
  float var  = sq * (1.f/DM) - mean*mean;
  float rstd = rsqrtf(var + 1e-5f);
  f32x4 gg = *reinterpret_cast<const f32x4*>(g   + lane*4);
  f32x4 bb = *reinterpret_cast<const f32x4*>(bta + lane*4);
  unsigned short* o = out + row*DM + lane*4;
  o[0] = f2bf((v.x-mean)*rstd*gg.x + bb.x);
  o[1] = f2bf((v.y-mean)*rstd*gg.y + bb.y);
  o[2] = f2bf((v.z-mean)*rstd*gg.z + bb.z);
  o[3] = f2bf((v.w-mean)*rstd*gg.w + bb.w);
}

// ======== LDS double-buffered bf16 MFMA GEMM (m97 structure) ========
// C[M,N] = A[M,K] @ W[N,K]^T, 128x128 block tile, BK=32, 4 waves (2x2), 4x4 frags/wave
// OUTMODE 0: f32 store, 1: bf16 store, 2: f32 accumulate (C += )
template<int OUTMODE>
__global__ __launch_bounds__(256) void gemm_lds(const unsigned short* __restrict__ A,
                                                const unsigned short* __restrict__ W,
                                                void* __restrict__ Cout, int N, int K){
  __shared__ __align__(16) unsigned short lds[2][2][128*32];
  int tid  = threadIdx.x;
  int wave = tid >> 6, lane = tid & 63;
  int wr = wave >> 1, wc = wave & 1;
  int mblock = blockIdx.y*128, nblock = blockIdx.x*128;
  int l15 = lane & 15, ks = (lane >> 4) * 8;
  int srow = lane >> 2;        // staging: 4 lanes per row
  int scol = (lane & 3) * 8;   // ushort offset within row

  f32x4 acc[4][4] = {};

  auto stage = [&](int buf, int k0){
    #pragma unroll
    for (int j=0; j<2; j++){
      int stripe = 4*j + wave;
      int rA = mblock + 16*stripe + srow;
      const unsigned short* ga = A + (size_t)rA*K + k0 + scol;
      __builtin_amdgcn_global_load_lds(ga, &lds[buf][0][stripe*512], 16, 0, 0);
      int rB = nblock + 16*stripe + srow; if (rB >= N) rB = N-1;
      const unsigned short* gb = W + (size_t)rB*K + k0 + scol;
      __builtin_amdgcn_global_load_lds(gb, &lds[buf][1][stripe*512], 16, 0, 0);
    }
  };

  stage(0, 0);
  __syncthreads();                 // drains vmcnt before first ds_read

  int nsteps = K >> 5;
  for (int s=0; s<nsteps; s++){
    int buf = s & 1;
    if (s+1 < nsteps) stage(buf^1, (s+1)*32);
    bf16x8 af[4], bfr[4];
    #pragma unroll
    for (int mf=0; mf<4; mf++)
      af[mf] = *(const bf16x8*)&lds[buf][0][(wr*64 + mf*16 + l15)*32 + ks];
    #pragma unroll
    for (int nf=0; nf<4; nf++)
      bfr[nf] = *(const bf16x8*)&lds[buf][1][(wc*64 + nf*16 + l15)*32 + ks];
    #pragma unroll
    for (int mf=0; mf<4; mf++)
      #pragma unroll
      for (int nf=0; nf<4; nf++)
        acc[mf][nf] = __builtin_amdgcn_mfma_f32_16x16x32_bf16(af[mf], bfr[nf], acc[mf][nf], 0,0,0);
    __syncthreads();               // drain staged tile + protect buf reuse
  }

  int rb = mblock + wr*64 + (lane >> 4)*4;
  #pragma unroll
  for (int mf=0; mf<4; mf++){
    #pragma unroll
    for (int nf=0; nf<4; nf++){
      int col = nblock + wc*64 + nf*16 + l15;
      if (col < N){
        #pragma unroll
        for (int j=0; j<4; j++){
          size_t idx = (size_t)(rb + mf*16 + j)*N + col;
          if (OUTMODE == 0)      ((float*)Cout)[idx] = acc[mf][nf][j];
          else if (OUTMODE == 1) ((unsigned short*)Cout)[idx] = f2bf(acc[mf][nf][j]);
          else                   ((float*)Cout)[idx] += acc[mf][nf][j];
        }
      }
    }
  }
}

// ---------------- depthwise causal conv(4) + bias + SiLU: xz[:, :512] -> u bf16 ----------------
__global__ void conv_kernel(const unsigned short* __restrict__ xz, const float* __restrict__ cw,
                            const float* __restrict__ cb, unsigned short* __restrict__ u){
  size_t idx = (size_t)blockIdx.x*256 + threadIdx.x;  // over MROWS*512
  int d = (int)(idx & 511);
  size_t row = idx >> 9;
  int l = (int)(row & (SEQ-1));
  float w0 = cw[d*4+0], w1 = cw[d*4+1], w2 = cw[d*4+2], w3 = cw[d*4+3];
  float acc = cb[d];
  const unsigned short* base = xz + row*1024 + d;
  acc += bf2f(base[0]) * w3;
  if (l >= 1) acc += bf2f(*(base - 1024)) * w2;
  if (l >= 2) acc += bf2f(*(base - 2048)) * w1;
  if (l >= 3) acc += bf2f(*(base - 3072)) * w0;
  float s = acc / (1.f + expf(-acc));
  u[row*512 + d] = f2bf(s);
}

// ---------------- delta = softplus(dt @ W_dt^T + b_dt), bf16 out ----------------
__global__ void delta_kernel(const float* __restrict__ xdb, const float* __restrict__ Wdt,
                             const float* __restrict__ bdt, unsigned short* __restrict__ delta){
  __shared__ float sdt[16];
  size_t row = blockIdx.x;
  int d = threadIdx.x;  // 512 threads
  if (d < 16) sdt[d] = xdb[row*48 + d];
  __syncthreads();
  f32x4 w0 = *reinterpret_cast<const f32x4*>(Wdt + d*16 + 0);
  f32x4 w1 = *reinterpret_cast<const f32x4*>(Wdt + d*16 + 4);
  f32x4 w2 = *reinterpret_cast<const f32x4*>(Wdt + d*16 + 8);
  f32x4 w3 = *reinterpret_cast<const f32x4*>(Wdt + d*16 + 12);
  float acc = bdt[d];
  acc += sdt[0]*w0.x + sdt[1]*w0.y + sdt[2]*w0.z + sdt[3]*w0.w;
  acc += sdt[4]*w1.x + sdt[5]*w1.y + sdt[6]*w1.z + sdt[7]*w1.w;
  acc += sdt[8]*w2.x + sdt[9]*w2.y + sdt[10]*w2.z + sdt[11]*w2.w;
  acc += sdt[12]*w3.x + sdt[13]*w3.y + sdt[14]*w3.z + sdt[15]*w3.w;
  float sp = (acc > 20.f) ? acc : log1pf(expf(acc));
  delta[row*512 + d] = f2bf(sp);
}

// ================= SSM chunked scan, lane-per-d layout =================
template<bool POW>
__device__ __forceinline__ void pass1_body(
    const unsigned short* dptr, const unsigned short* uptr, const float* bptr,
    const float* A, float* h, float& sumdv){
  #pragma unroll 2
  for (int l=0; l<CL; l++){
    float dv = bf2f(dptr[(size_t)l*512]);
    float uv = bf2f(uptr[(size_t)l*512]);
    const float* br = bptr + (size_t)l*48;
    f32x4 B0 = *(const f32x4*)(br + 0);
    f32x4 B1 = *(const f32x4*)(br + 4);
    f32x4 B2 = *(const f32x4*)(br + 8);
    f32x4 B3 = *(const f32x4*)(br + 12);
    float t = dv*uv;
    sumdv += dv;
    if (POW){
      float a0 = __expf(dv*A[0]);
      float ap = 1.f;
      #pragma unroll
      for (int i=0;i<16;i++){ ap *= a0; h[i] = ap*h[i] + t*BSEL(i); }
    } else {
      #pragma unroll
      for (int i=0;i<16;i++){ float a = __expf(dv*A[i]); h[i] = a*h[i] + t*BSEL(i); }
    }
  }
}

__global__ void __launch_bounds__(256) scan_pass1(
    const unsigned short* __restrict__ dlt, const unsigned short* __restrict__ u,
    const float* __restrict__ xdb, const float* __restrict__ Alog,
    float* __restrict__ sumdvB, float* __restrict__ Hbuf){
  int bid = blockIdx.x;               // ((b*CCH)+c)*2 + half
  int half = bid & 1;
  int c = (bid >> 1) & (CCH-1);
  int b = bid >> 7;
  int wave = threadIdx.x >> 6, lane = threadIdx.x & 63;
  int d = half*256 + wave*64 + lane;
  const float* ar = Alog + d*16;
  f32x4 Aq0 = *(const f32x4*)(ar+0), Aq1 = *(const f32x4*)(ar+4);
  f32x4 Aq2 = *(const f32x4*)(ar+8), Aq3 = *(const f32x4*)(ar+12);
  float A[16];
  #pragma unroll
  for (int i=0;i<16;i++) A[i] = -__expf(ASEL(i));
  bool pw = true;
  #pragma unroll
  for (int i=1;i<16;i++) pw = pw && (fabsf(A[i] - (float)(i+1)*A[0]) <= 1e-3f*fabsf(A[i]));
  float h[16];
  #pragma unroll
  for (int i=0;i<16;i++) h[i] = 0.f;
  float sumdv = 0.f;
  size_t rowbase = (size_t)b*SEQ + (size_t)c*CL;
  const unsigned short* dptr = dlt + rowbase*512 + d;
  const unsigned short* uptr = u   + rowbase*512 + d;
  const float*          bptr = xdb + rowbase*48 + 16;
  if (pw) pass1_body<true >(dptr, uptr, bptr, A, h, sumdv);
  else    pass1_body<false>(dptr, uptr, bptr, A, h, sumdv);
  size_t o = (size_t)(c*BATCH + b)*512 + d;
  sumdvB[o] = sumdv;
  float* Hp = Hbuf + o*16;
  *(f32x4*)(Hp+ 0) = f32x4{h[0],h[1],h[2],h[3]};
  *(f32x4*)(Hp+ 4) = f32x4{h[4],h[5],h[6],h[7]};
  *(f32x4*)(Hp+ 8) = f32x4{h[8],h[9],h[10],h[11]};
  *(f32x4*)(Hp+12) = f32x4{h[12],h[13],h[14],h[15]};
}

// pass2: thread per (b,d,n): serial combine over chunks; Hbuf[c] := h_init(c)
__global__ void __launch_bounds__(256) scan_pass2(
    const float* __restrict__ sumdvB, const float* __restrict__ Alog,
    float* __restrict__ Hbuf){
  int gid = blockIdx.x*256 + threadIdx.x;   // b*8192 + d*16 + n
  float A = -__expf(Alog[gid & 8191]);
  float H = 0.f;
  for (int c=0; c<CCH; c++){
    float s  = sumdvB[(size_t)c*(BATCH*DI) + (gid>>4)];
    size_t o = (size_t)c*SC + gid;
    float hf = Hbuf[o];
    Hbuf[o] = H;
    H = __expf(A*s)*H + hf;
  }
}

// pass3: re-run chunk from h_init; y = C.h + D*u; fused gate: g = y*silu(z); bf16 g over u
template<bool POW>
__device__ __forceinline__ void pass3_body(
    const unsigned short* dptr, unsigned short* uptr, const unsigned short* zptr,
    const float* bptr, const float* A, float* h, float Dd){
  #pragma unroll 2
  for (int l=0; l<CL; l++){
    float dv = bf2f(dptr[(size_t)l*512]);
    float uv = bf2f(uptr[(size_t)l*512]);
    float zv = bf2f(zptr[(size_t)l*1024]);
    const float* br = bptr + (size_t)l*48;
    f32x4 B0 = *(const f32x4*)(br + 0);
    f32x4 B1 = *(const f32x4*)(br + 4);
    f32x4 B2 = *(const f32x4*)(br + 8);
    f32x4 B3 = *(const f32x4*)(br + 12);
    f32x4 C0 = *(const f32x4*)(br + 16);
    f32x4 C1 = *(const f32x4*)(br + 20);
    f32x4 C2 = *(const f32x4*)(br + 24);
    f32x4 C3 = *(const f32x4*)(br + 28);
    float t = dv*uv;
    float p0=0.f,p1=0.f,p2=0.f,p3=0.f;
    if (POW){
      float a0 = __expf(dv*A[0]);
      float ap = 1.f;
      #pragma unroll
      for (int i=0;i<16;i++){
        ap *= a0;
        h[i] = ap*h[i] + t*BSEL(i);
        float hp = h[i]*CSEL(i);
        if ((i&3)==0) p0 += hp; else if ((i&3)==1) p1 += hp; else if ((i&3)==2) p2 += hp; else p3 += hp;
      }
    } else {
      #pragma unroll
      for (int i=0;i<16;i++){
        float a = __expf(dv*A[i]);
        h[i] = a*h[i] + t*BSEL(i);
        float hp = h[i]*CSEL(i);
        if ((i&3)==0) p0 += hp; else if ((i&3)==1) p1 += hp; else if ((i&3)==2) p2 += hp; else p3 += hp;
      }
    }
    float y = (p0+p1) + (p2+p3) + Dd*uv;
    float g = y * (zv / (1.f + __expf(-zv)));
    uptr[(size_t)l*512] = f2bf(g);
  }
}

__global__ void __launch_bounds__(256) scan_pass3(
    const unsigned short* __restrict__ dlt, unsigned short* __restrict__ u,
    const unsigned short* __restrict__ xz, const float* __restrict__ xdb,
    const float* __restrict__ Alog, const float* __restrict__ Dp,
    const float* __restrict__ Hbuf){
  int bid = blockIdx.x;
  int half = bid & 1;
  int c = (bid >> 1) & (CCH-1);
  int b = bid >> 7;
  int wave = threadIdx.x >> 6, lane = threadIdx.x & 63;
  int d = half*256 + wave*64 + lane;
  const float* ar = Alog + d*16;
  f32x4 Aq0 = *(const f32x4*)(ar+0), Aq1 = *(const f32x4*)(ar+4);
  f32x4 Aq2 = *(const f32x4*)(ar+8), Aq3 = *(const f32x4*)(ar+12);
  float A[16];
  #pragma unroll
  for (int i=0;i<16;i++) A[i] = -__expf(ASEL(i));
  bool pw = true;
  #pragma unroll
  for (int i=1;i<16;i++) pw = pw && (fabsf(A[i] - (float)(i+1)*A[0]) <= 1e-3f*fabsf(A[i]));
  float Dd = Dp[d];
  size_t o = (size_t)(c*BATCH + b)*512 + d;
  const float* Hp = Hbuf + o*16;
  f32x4 h0 = *(const f32x4*)(Hp+0), h1 = *(const f32x4*)(Hp+4);
  f32x4 h2 = *(const f32x4*)(Hp+8), h3 = *(const f32x4*)(Hp+12);
  float h[16] = {h0.x,h0.y,h0.z,h0.w, h1.x,h1.y,h1.z,h1.w,
                 h2.x,h2.y,h2.z,h2.w, h3.x,h3.y,h3.z,h3.w};
  size_t rowbase = (size_t)b*SEQ + (size_t)c*CL;
  const unsigned short* dptr = dlt + rowbase*512 + d;
  unsigned short*       uptr = u   + rowbase*512 + d;
  const unsigned short* zptr = xz  + rowbase*1024 + 512 + d;
  const float*          bptr = xdb + rowbase*48 + 16;
  if (pw) pass3_body<true >(dptr, uptr, zptr, bptr, A, h, Dd);
  else    pass3_body<false>(dptr, uptr, zptr, bptr, A, h, Dd);
}

extern "C" void kernel_launch(void* const* d_in, const int* in_sizes, int n_in,
                              void* d_out, int out_size, void* d_ws, size_t ws_size,
                              hipStream_t stream){
  (void)in_sizes; (void)n_in; (void)out_size; (void)ws_size;
  const float* x      = (const float*)d_in[0];
  const float* W_in   = (const float*)d_in[1];
  const float* conv_w = (const float*)d_in[2];
  const float* conv_b = (const float*)d_in[3];
  const float* W_x    = (const float*)d_in[4];
  const float* W_dt   = (const float*)d_in[5];
  const float* b_dt   = (const float*)d_in[6];
  const float* A_log  = (const float*)d_in[7];
  const float* Dp     = (const float*)d_in[8];
  const float* W_out  = (const float*)d_in[9];
  const float* ln_g   = (const float*)d_in[10];
  const float* ln_b   = (const float*)d_in[11];
  float* out = (float*)d_out;

  // workspace carve-up (~198 MB)
  char* p = (char*)d_ws;
  auto alloc = [&](size_t bytes)->char*{
    char* r = p; p += (bytes + 255) & ~(size_t)255; return r;
  };
  float*          hbuf   = (float*)alloc((size_t)MROWS*DM*4);           // 33.5 MB residual f32
  unsigned short* xzb    = (unsigned short*)alloc((size_t)MROWS*1024*2);// 67 MB
  unsigned short* ubuf   = (unsigned short*)alloc((size_t)MROWS*DI*2);  // 33.5 MB (u, then gated g)
  unsigned short* lnb    = (unsigned short*)alloc((size_t)MROWS*DI*2);  // 33.5 MB shared: lnb / delta
  unsigned short* dlt    = lnb;                                         // alias (disjoint live ranges)
  float*          xdb    = (float*)alloc((size_t)MROWS*48*4);           // 6.3 MB
  unsigned short* WinB   = (unsigned short*)alloc((size_t)NL*1024*DM*2);// 3.1 MB
  unsigned short* WxB    = (unsigned short*)alloc((size_t)NL*48*DI*2);  // 0.3 MB
  unsigned short* WoutB  = (unsigned short*)alloc((size_t)NL*DM*DI*2);  // 1.6 MB
  float*          sumdvB = (float*)alloc((size_t)CCH*BATCH*DI*4);       // 1.05 MB
  float*          Hbuf   = (float*)alloc((size_t)CCH*SC*4);             // 16.8 MB

  // weight conversion
  {
    int n1 = NL*1024*DM;  cvt_bf16<<<(n1+255)/256, 256, 0, stream>>>(W_in,  WinB,  n1);
    int n2 = NL*48*DI;    cvt_bf16<<<(n2+255)/256, 256, 0, stream>>>(W_x,   WxB,   n2);
    int n3 = NL*DM*DI;    cvt_bf16<<<(n3+255)/256, 256, 0, stream>>>(W_out, WoutB, n3);
  }

  transpose_in<<<dim3(SEQ/32, DM/32, BATCH), dim3(32,8), 0, stream>>>(x, hbuf);

  for (int i=0; i<NL; i++){
    const unsigned short* Wi = WinB  + (size_t)i*1024*DM;
    const unsigned short* Wx = WxB   + (size_t)i*48*DI;
    const unsigned short* Wo = WoutB + (size_t)i*DM*DI;
    const float* Al = A_log + (size_t)i*DI*DS;

    ln_kernel<<<MROWS/4, 256, 0, stream>>>(hbuf, ln_g + i*DM, ln_b + i*DM, lnb);

    // xz = ln @ W_in^T  [M,1024] bf16
    gemm_lds<1><<<dim3(1024/128, MROWS/128), 256, 0, stream>>>(lnb, Wi, xzb, 1024, DM);

    conv_kernel<<<(size_t)MROWS*DI/256, 256, 0, stream>>>(xzb, conv_w + (size_t)i*DI*4,
                                                          conv_b + i*DI, ubuf);

    // xdb = u @ W_x^T  [M,48] f32
    gemm_lds<0><<<dim3(1, MROWS/128), 256, 0, stream>>>(ubuf, Wx, xdb, 48, DI);

    delta_kernel<<<MROWS, 512, 0, stream>>>(xdb, W_dt + (size_t)i*DI*DTR, b_dt + i*DI, dlt);

    scan_pass1<<<BATCH*CCH*2, 256, 0, stream>>>(dlt, ubuf, xdb, Al, sumdvB, Hbuf);
    scan_pass2<<<SC/256, 256, 0, stream>>>(sumdvB, Al, Hbuf);
    scan_pass3<<<BATCH*CCH*2, 256, 0, stream>>>(dlt, ubuf, xzb, xdb, Al, Dp + i*DI, Hbuf);

    // h += g @ W_out^T  [M,256] f32 accumulate
    gemm_lds<2><<<dim3(DM/128, MROWS/128), 256, 0, stream>>>(ubuf, Wo, hbuf, DM, DI);
  }

  transpose_out<<<dim3(SEQ/32, DM/32, BATCH), dim3(32,8), 0, stream>>>(hbuf, out);
}

// Round 7
// 1819.722 us; speedup vs baseline: 7.1249x; 1.1256x over previous
//
#include <hip/hip_runtime.h>

#define BATCH 8
#define SEQ   4096
#define DM    256
#define DI    512
#define DS    16
#define DTR   16
#define NL    6
#define MROWS (BATCH*SEQ)   // 32768
#define CCH   64            // scan chunks
#define CL    (SEQ/CCH)     // 64 steps per chunk
#define SC    (BATCH*DI*DS) // 65536 per-chunk scan states

typedef float  f32x4 __attribute__((ext_vector_type(4)));
typedef __bf16 bf16x8 __attribute__((ext_vector_type(8)));

__device__ __forceinline__ float bf2f(unsigned short b){
  unsigned u = ((unsigned)b) << 16;
  return __builtin_bit_cast(float, u);
}
__device__ __forceinline__ unsigned short f2bf(float f){
  unsigned u = __builtin_bit_cast(unsigned, f);
  unsigned r = u + 0x7FFFu + ((u >> 16) & 1u);
  return (unsigned short)(r >> 16);
}

#define ASEL(i) ((i)<4?Aq0[(i)&3]:(i)<8?Aq1[(i)&3]:(i)<12?Aq2[(i)&3]:Aq3[(i)&3])
#define BSEL(i) ((i)<4?B0[(i)&3]:(i)<8?B1[(i)&3]:(i)<12?B2[(i)&3]:B3[(i)&3])
#define CSEL(i) ((i)<4?C0[(i)&3]:(i)<8?C1[(i)&3]:(i)<12?C2[(i)&3]:C3[(i)&3])

// ---------------- transpose x [B,256,L] f32 -> h [(b*L+l)*256+c] f32 ----------------
__global__ void transpose_in(const float* __restrict__ x, float* __restrict__ h){
  __shared__ float tile[32][33];
  int b = blockIdx.z;
  int l0 = blockIdx.x*32, c0 = blockIdx.y*32;
  int tx = threadIdx.x, ty = threadIdx.y;
  #pragma unroll
  for (int i=0;i<4;i++)
    tile[ty+8*i][tx] = x[((size_t)(b*DM + c0+ty+8*i))*SEQ + l0 + tx];
  __syncthreads();
  #pragma unroll
  for (int i=0;i<4;i++)
    h[((size_t)(b*SEQ + l0+ty+8*i))*DM + c0 + tx] = tile[tx][ty+8*i];
}

// ---------------- transpose h -> out [B,256,L] ----------------
__global__ void transpose_out(const float* __restrict__ h, float* __restrict__ out){
  __shared__ float tile[32][33];
  int b = blockIdx.z;
  int l0 = blockIdx.x*32, c0 = blockIdx.y*32;
  int tx = threadIdx.x, ty = threadIdx.y;
  #pragma unroll
  for (int i=0;i<4;i++)
    tile[ty+8*i][tx] = h[((size_t)(b*SEQ + l0+ty+8*i))*DM + c0 + tx];
  __syncthreads();
  #pragma unroll
  for (int i=0;i<4;i++)
    out[((size_t)(b*DM + c0+ty+8*i))*SEQ + l0 + tx] = tile[tx][ty+8*i];
}

// ---------------- f32 -> bf16 convert ----------------
__global__ void cvt_bf16(const float* __restrict__ in, unsigned short* __restrict__ out, int n){
  int i = blockIdx.x*256 + threadIdx.x;
  if (i < n) out[i] = f2bf(in[i]);
}

// ---------------- W_eff[l][d][k] = sum_r W_dt[l][d][r] * W_x[l][r][k], bf16 out ----------------
__global__ void weff_kernel(const float* __restrict__ Wdt, const float* __restrict__ Wx,
                            unsigned short* __restrict__ Weff){
  int idx = blockIdx.x*256 + threadIdx.x;   // over NL*512*512
  int l = idx >> 18;
  int r = idx & 262143;
  int d = r >> 9, k = r & 511;
  const float* wd = Wdt + (size_t)l*DI*DTR + d*DTR;
  const float* wx = Wx  + (size_t)l*48*DI + k;
  float acc = 0.f;
  #pragma unroll
  for (int j=0;j<16;j++) acc += wd[j]*wx[(size_t)j*DI];
  Weff[idx] = f2bf(acc);
}

// ---------------- LayerNorm over 256 channels, one wave per row, bf16 out ----------------
__global__ void ln_kernel(const float* __restrict__ h, const float* __restrict__ g,
                          const float* __restrict__ bta, unsigned short* __restrict__ out){
  int wave = threadIdx.x >> 6, lane = threadIdx.x & 63;
  size_t row = (size_t)blockIdx.x*4 + wave;
  const float* hr = h + row*DM;
  f32x4 v = *reinterpret_cast<const f32x4*>(hr + lane*4);
  float s  = v.x + v.y + v.z + v.w;
  float sq = v.x*v.x + v.y*v.y + v.z*v.z + v.w*v.w;
  #pragma unroll
  for (int off=32; off; off>>=1){
    s  += __shfl_xor(s,  off, 64);
    sq += __shfl_xor(sq, off, 64);
  }
  float mean = s * (1.f/DM);
  float var  = sq * (1.f/DM) - mean*mean;
  float rstd = rsqrtf(var + 1e-5f);
  f32x4 gg = *reinterpret_cast<const f32x4*>(g   + lane*4);
  f32x4 bb = *reinterpret_cast<const f32x4*>(bta + lane*4);
  unsigned short* o = out + row*DM + lane*4;
  o[0] = f2bf((v.x-mean)*rstd*gg.x + bb.x);
  o[1] = f2bf((v.y-mean)*rstd*gg.y + bb.y);
  o[2] = f2bf((v.z-mean)*rstd*gg.z + bb.z);
  o[3] = f2bf((v.w-mean)*rstd*gg.w + bb.w);
}

// ======== LDS double-buffered bf16 MFMA GEMM (m97 structure) ========
// C[M,N] = A[M,K] @ W[N,K]^T, 128x128 block tile, BK=32, 4 waves (2x2), 4x4 frags/wave
// OUTMODE 0: f32 store, 1: bf16 store, 2: f32 accumulate, 3: softplus(acc+bias) bf16 store
template<int OUTMODE>
__global__ __launch_bounds__(256) void gemm_lds(const unsigned short* __restrict__ A,
                                                const unsigned short* __restrict__ W,
                                                void* __restrict__ Cout,
                                                const float* __restrict__ bias, int N, int K){
  __shared__ __align__(16) unsigned short lds[2][2][128*32];
  int tid  = threadIdx.x;
  int wave = tid >> 6, lane = tid & 63;
  int wr = wave >> 1, wc = wave & 1;
  int mblock = blockIdx.y*128, nblock = blockIdx.x*128;
  int l15 = lane & 15, ks = (lane >> 4) * 8;
  int srow = lane >> 2;        // staging: 4 lanes per row
  int scol = (lane & 3) * 8;   // ushort offset within row

  f32x4 acc[4][4] = {};

  auto stage = [&](int buf, int k0){
    #pragma unroll
    for (int j=0; j<2; j++){
      int stripe = 4*j + wave;
      int rA = mblock + 16*stripe + srow;
      const unsigned short* ga = A + (size_t)rA*K + k0 + scol;
      __builtin_amdgcn_global_load_lds(ga, &lds[buf][0][stripe*512], 16, 0, 0);
      int rB = nblock + 16*stripe + srow; if (rB >= N) rB = N-1;
      const unsigned short* gb = W + (size_t)rB*K + k0 + scol;
      __builtin_amdgcn_global_load_lds(gb, &lds[buf][1][stripe*512], 16, 0, 0);
    }
  };

  stage(0, 0);
  __syncthreads();                 // drains vmcnt before first ds_read

  int nsteps = K >> 5;
  for (int s=0; s<nsteps; s++){
    int buf = s & 1;
    if (s+1 < nsteps) stage(buf^1, (s+1)*32);
    bf16x8 af[4], bfr[4];
    #pragma unroll
    for (int mf=0; mf<4; mf++)
      af[mf] = *(const bf16x8*)&lds[buf][0][(wr*64 + mf*16 + l15)*32 + ks];
    #pragma unroll
    for (int nf=0; nf<4; nf++)
      bfr[nf] = *(const bf16x8*)&lds[buf][1][(wc*64 + nf*16 + l15)*32 + ks];
    #pragma unroll
    for (int mf=0; mf<4; mf++)
      #pragma unroll
      for (int nf=0; nf<4; nf++)
        acc[mf][nf] = __builtin_amdgcn_mfma_f32_16x16x32_bf16(af[mf], bfr[nf], acc[mf][nf], 0,0,0);
    __syncthreads();               // drain staged tile + protect buf reuse
  }

  int rb = mblock + wr*64 + (lane >> 4)*4;
  #pragma unroll
  for (int mf=0; mf<4; mf++){
    #pragma unroll
    for (int nf=0; nf<4; nf++){
      int col = nblock + wc*64 + nf*16 + l15;
      if (col < N){
        float bv = (OUTMODE == 3) ? bias[col] : 0.f;
        #pragma unroll
        for (int j=0; j<4; j++){
          size_t idx = (size_t)(rb + mf*16 + j)*N + col;
          if (OUTMODE == 0)      ((float*)Cout)[idx] = acc[mf][nf][j];
          else if (OUTMODE == 1) ((unsigned short*)Cout)[idx] = f2bf(acc[mf][nf][j]);
          else if (OUTMODE == 2) ((float*)Cout)[idx] += acc[mf][nf][j];
          else {
            float v = acc[mf][nf][j] + bv;
            float sp = fmaxf(v, 0.f) + __logf(1.f + __expf(-fabsf(v)));
            ((unsigned short*)Cout)[idx] = f2bf(sp);
          }
        }
      }
    }
  }
}

// ---------------- depthwise causal conv(4) + bias + SiLU: xz[:, :512] -> u bf16 ----------------
__global__ void conv_kernel(const unsigned short* __restrict__ xz, const float* __restrict__ cw,
                            const float* __restrict__ cb, unsigned short* __restrict__ u){
  size_t idx = (size_t)blockIdx.x*256 + threadIdx.x;  // over MROWS*512
  int d = (int)(idx & 511);
  size_t row = idx >> 9;
  int l = (int)(row & (SEQ-1));
  float w0 = cw[d*4+0], w1 = cw[d*4+1], w2 = cw[d*4+2], w3 = cw[d*4+3];
  float acc = cb[d];
  const unsigned short* base = xz + row*1024 + d;
  acc += bf2f(base[0]) * w3;
  if (l >= 1) acc += bf2f(*(base - 1024)) * w2;
  if (l >= 2) acc += bf2f(*(base - 2048)) * w1;
  if (l >= 3) acc += bf2f(*(base - 3072)) * w0;
  float s = acc / (1.f + expf(-acc));
  u[row*512 + d] = f2bf(s);
}

// ================= SSM chunked scan, lane-per-d layout =================
// xdbc layout: [M][32] f32: cols 0..15 = B, 16..31 = C
template<bool POW>
__device__ __forceinline__ void pass1_body(
    const unsigned short* dptr, const unsigned short* uptr, const float* bptr,
    const float* A, float* h, float& sumdv){
  #pragma unroll 2
  for (int l=0; l<CL; l++){
    float dv = bf2f(dptr[(size_t)l*512]);
    float uv = bf2f(uptr[(size_t)l*512]);
    const float* br = bptr + (size_t)l*32;
    f32x4 B0 = *(const f32x4*)(br + 0);
    f32x4 B1 = *(const f32x4*)(br + 4);
    f32x4 B2 = *(const f32x4*)(br + 8);
    f32x4 B3 = *(const f32x4*)(br + 12);
    float t = dv*uv;
    sumdv += dv;
    if (POW){
      float a0 = __expf(dv*A[0]);
      float ap = 1.f;
      #pragma unroll
      for (int i=0;i<16;i++){ ap *= a0; h[i] = ap*h[i] + t*BSEL(i); }
    } else {
      #pragma unroll
      for (int i=0;i<16;i++){ float a = __expf(dv*A[i]); h[i] = a*h[i] + t*BSEL(i); }
    }
  }
}

__global__ void __launch_bounds__(256) scan_pass1(
    const unsigned short* __restrict__ dlt, const unsigned short* __restrict__ u,
    const float* __restrict__ xdb, const float* __restrict__ Alog,
    float* __restrict__ sumdvB, float* __restrict__ Hbuf){
  int bid = blockIdx.x;               // ((b*CCH)+c)*2 + half
  int half = bid & 1;
  int c = (bid >> 1) & (CCH-1);
  int b = bid >> 7;
  int wave = threadIdx.x >> 6, lane = threadIdx.x & 63;
  int d = half*256 + wave*64 + lane;
  const float* ar = Alog + d*16;
  f32x4 Aq0 = *(const f32x4*)(ar+0), Aq1 = *(const f32x4*)(ar+4);
  f32x4 Aq2 = *(const f32x4*)(ar+8), Aq3 = *(const f32x4*)(ar+12);
  float A[16];
  #pragma unroll
  for (int i=0;i<16;i++) A[i] = -__expf(ASEL(i));
  bool pw = true;
  #pragma unroll
  for (int i=1;i<16;i++) pw = pw && (fabsf(A[i] - (float)(i+1)*A[0]) <= 1e-3f*fabsf(A[i]));
  float h[16];
  #pragma unroll
  for (int i=0;i<16;i++) h[i] = 0.f;
  float sumdv = 0.f;
  size_t rowbase = (size_t)b*SEQ + (size_t)c*CL;
  const unsigned short* dptr = dlt + rowbase*512 + d;
  const unsigned short* uptr = u   + rowbase*512 + d;
  const float*          bptr = xdb + rowbase*32;
  if (pw) pass1_body<true >(dptr, uptr, bptr, A, h, sumdv);
  else    pass1_body<false>(dptr, uptr, bptr, A, h, sumdv);
  size_t o = (size_t)(c*BATCH + b)*512 + d;
  sumdvB[o] = sumdv;
  float* Hp = Hbuf + o*16;
  *(f32x4*)(Hp+ 0) = f32x4{h[0],h[1],h[2],h[3]};
  *(f32x4*)(Hp+ 4) = f32x4{h[4],h[5],h[6],h[7]};
  *(f32x4*)(Hp+ 8) = f32x4{h[8],h[9],h[10],h[11]};
  *(f32x4*)(Hp+12) = f32x4{h[12],h[13],h[14],h[15]};
}

// pass2: thread per (b,d,n): serial combine over chunks; Hbuf[c] := h_init(c)
__global__ void __launch_bounds__(256) scan_pass2(
    const float* __restrict__ sumdvB, const float* __restrict__ Alog,
    float* __restrict__ Hbuf){
  int gid = blockIdx.x*256 + threadIdx.x;   // b*8192 + d*16 + n
  float A = -__expf(Alog[gid & 8191]);
  float H = 0.f;
  for (int c=0; c<CCH; c++){
    float s  = sumdvB[(size_t)c*(BATCH*DI) + (gid>>4)];
    size_t o = (size_t)c*SC + gid;
    float hf = Hbuf[o];
    Hbuf[o] = H;
    H = __expf(A*s)*H + hf;
  }
}

// pass3: re-run chunk from h_init; y = C.h + D*u; fused gate: g = y*silu(z); bf16 g over u
template<bool POW>
__device__ __forceinline__ void pass3_body(
    const unsigned short* dptr, unsigned short* uptr, const unsigned short* zptr,
    const float* bptr, const float* A, float* h, float Dd){
  #pragma unroll 2
  for (int l=0; l<CL; l++){
    float dv = bf2f(dptr[(size_t)l*512]);
    float uv = bf2f(uptr[(size_t)l*512]);
    float zv = bf2f(zptr[(size_t)l*1024]);
    const float* br = bptr + (size_t)l*32;
    f32x4 B0 = *(const f32x4*)(br + 0);
    f32x4 B1 = *(const f32x4*)(br + 4);
    f32x4 B2 = *(const f32x4*)(br + 8);
    f32x4 B3 = *(const f32x4*)(br + 12);
    f32x4 C0 = *(const f32x4*)(br + 16);
    f32x4 C1 = *(const f32x4*)(br + 20);
    f32x4 C2 = *(const f32x4*)(br + 24);
    f32x4 C3 = *(const f32x4*)(br + 28);
    float t = dv*uv;
    float p0=0.f,p1=0.f,p2=0.f,p3=0.f;
    if (POW){
      float a0 = __expf(dv*A[0]);
      float ap = 1.f;
      #pragma unroll
      for (int i=0;i<16;i++){
        ap *= a0;
        h[i] = ap*h[i] + t*BSEL(i);
        float hp = h[i]*CSEL(i);
        if ((i&3)==0) p0 += hp; else if ((i&3)==1) p1 += hp; else if ((i&3)==2) p2 += hp; else p3 += hp;
      }
    } else {
      #pragma unroll
      for (int i=0;i<16;i++){
        float a = __expf(dv*A[i]);
        h[i] = a*h[i] + t*BSEL(i);
        float hp = h[i]*CSEL(i);
        if ((i&3)==0) p0 += hp; else if ((i&3)==1) p1 += hp; else if ((i&3)==2) p2 += hp; else p3 += hp;
      }
    }
    float y = (p0+p1) + (p2+p3) + Dd*uv;
    float g = y * (zv / (1.f + __expf(-zv)));
    uptr[(size_t)l*512] = f2bf(g);
  }
}

__global__ void __launch_bounds__(256) scan_pass3(
    const unsigned short* __restrict__ dlt, unsigned short* __restrict__ u,
    const unsigned short* __restrict__ xz, const float* __restrict__ xdb,
    const float* __restrict__ Alog, const float* __restrict__ Dp,
    const float* __restrict__ Hbuf){
  int bid = blockIdx.x;
  int half = bid & 1;
  int c = (bid >> 1) & (CCH-1);
  int b = bid >> 7;
  int wave = threadIdx.x >> 6, lane = threadIdx.x & 63;
  int d = half*256 + wave*64 + lane;
  const float* ar = Alog + d*16;
  f32x4 Aq0 = *(const f32x4*)(ar+0), Aq1 = *(const f32x4*)(ar+4);
  f32x4 Aq2 = *(const f32x4*)(ar+8), Aq3 = *(const f32x4*)(ar+12);
  float A[16];
  #pragma unroll
  for (int i=0;i<16;i++) A[i] = -__expf(ASEL(i));
  bool pw = true;
  #pragma unroll
  for (int i=1;i<16;i++) pw = pw && (fabsf(A[i] - (float)(i+1)*A[0]) <= 1e-3f*fabsf(A[i]));
  float Dd = Dp[d];
  size_t o = (size_t)(c*BATCH + b)*512 + d;
  const float* Hp = Hbuf + o*16;
  f32x4 h0 = *(const f32x4*)(Hp+0), h1 = *(const f32x4*)(Hp+4);
  f32x4 h2 = *(const f32x4*)(Hp+8), h3 = *(const f32x4*)(Hp+12);
  float h[16] = {h0.x,h0.y,h0.z,h0.w, h1.x,h1.y,h1.z,h1.w,
                 h2.x,h2.y,h2.z,h2.w, h3.x,h3.y,h3.z,h3.w};
  size_t rowbase = (size_t)b*SEQ + (size_t)c*CL;
  const unsigned short* dptr = dlt + rowbase*512 + d;
  unsigned short*       uptr = u   + rowbase*512 + d;
  const unsigned short* zptr = xz  + rowbase*1024 + 512 + d;
  const float*          bptr = xdb + rowbase*32;
  if (pw) pass3_body<true >(dptr, uptr, zptr, bptr, A, h, Dd);
  else    pass3_body<false>(dptr, uptr, zptr, bptr, A, h, Dd);
}

extern "C" void kernel_launch(void* const* d_in, const int* in_sizes, int n_in,
                              void* d_out, int out_size, void* d_ws, size_t ws_size,
                              hipStream_t stream){
  (void)in_sizes; (void)n_in; (void)out_size; (void)ws_size;
  const float* x      = (const float*)d_in[0];
  const float* W_in   = (const float*)d_in[1];
  const float* conv_w = (const float*)d_in[2];
  const float* conv_b = (const float*)d_in[3];
  const float* W_x    = (const float*)d_in[4];
  const float* W_dt   = (const float*)d_in[5];
  const float* b_dt   = (const float*)d_in[6];
  const float* A_log  = (const float*)d_in[7];
  const float* Dp     = (const float*)d_in[8];
  const float* W_out  = (const float*)d_in[9];
  const float* ln_g   = (const float*)d_in[10];
  const float* ln_b   = (const float*)d_in[11];
  float* out = (float*)d_out;

  // workspace carve-up (~196 MB)
  char* p = (char*)d_ws;
  auto alloc = [&](size_t bytes)->char*{
    char* r = p; p += (bytes + 255) & ~(size_t)255; return r;
  };
  float*          hbuf   = (float*)alloc((size_t)MROWS*DM*4);           // 33.5 MB residual f32
  unsigned short* xzb    = (unsigned short*)alloc((size_t)MROWS*1024*2);// 67 MB
  unsigned short* ubuf   = (unsigned short*)alloc((size_t)MROWS*DI*2);  // 33.5 MB (u, then gated g)
  unsigned short* lnb    = (unsigned short*)alloc((size_t)MROWS*DI*2);  // 33.5 MB shared: lnb / delta
  unsigned short* dlt    = lnb;                                         // alias (disjoint live ranges)
  float*          xdbc   = (float*)alloc((size_t)MROWS*32*4);           // 4.2 MB (B,C)
  unsigned short* WinB   = (unsigned short*)alloc((size_t)NL*1024*DM*2);// 3.1 MB
  unsigned short* WxB    = (unsigned short*)alloc((size_t)NL*48*DI*2);  // 0.3 MB
  unsigned short* WoutB  = (unsigned short*)alloc((size_t)NL*DM*DI*2);  // 1.6 MB
  unsigned short* WeffB  = (unsigned short*)alloc((size_t)NL*DI*DI*2);  // 3.1 MB
  float*          sumdvB = (float*)alloc((size_t)CCH*BATCH*DI*4);       // 1.05 MB
  float*          Hbuf   = (float*)alloc((size_t)CCH*SC*4);             // 16.8 MB

  // weight conversion + W_eff precompute
  {
    int n1 = NL*1024*DM;  cvt_bf16<<<(n1+255)/256, 256, 0, stream>>>(W_in,  WinB,  n1);
    int n2 = NL*48*DI;    cvt_bf16<<<(n2+255)/256, 256, 0, stream>>>(W_x,   WxB,   n2);
    int n3 = NL*DM*DI;    cvt_bf16<<<(n3+255)/256, 256, 0, stream>>>(W_out, WoutB, n3);
    weff_kernel<<<NL*DI*DI/256, 256, 0, stream>>>(W_dt, W_x, WeffB);
  }

  transpose_in<<<dim3(SEQ/32, DM/32, BATCH), dim3(32,8), 0, stream>>>(x, hbuf);

  for (int i=0; i<NL; i++){
    const unsigned short* Wi = WinB  + (size_t)i*1024*DM;
    const unsigned short* Wx = WxB   + (size_t)i*48*DI + 16*DI;  // B,C rows only
    const unsigned short* Wo = WoutB + (size_t)i*DM*DI;
    const unsigned short* We = WeffB + (size_t)i*DI*DI;
    const float* Al = A_log + (size_t)i*DI*DS;

    ln_kernel<<<MROWS/4, 256, 0, stream>>>(hbuf, ln_g + i*DM, ln_b + i*DM, lnb);

    // xz = ln @ W_in^T  [M,1024] bf16
    gemm_lds<1><<<dim3(1024/128, MROWS/128), 256, 0, stream>>>(lnb, Wi, xzb, nullptr, 1024, DM);

    conv_kernel<<<(size_t)MROWS*DI/256, 256, 0, stream>>>(xzb, conv_w + (size_t)i*DI*4,
                                                          conv_b + i*DI, ubuf);

    // xdbc = u @ Wx[16:48]^T  [M,32] f32 (B,C)
    gemm_lds<0><<<dim3(1, MROWS/128), 256, 0, stream>>>(ubuf, Wx, xdbc, nullptr, 32, DI);

    // delta = softplus(u @ W_eff^T + b_dt)  [M,512] bf16
    gemm_lds<3><<<dim3(DI/128, MROWS/128), 256, 0, stream>>>(ubuf, We, dlt, b_dt + i*DI, DI, DI);

    scan_pass1<<<BATCH*CCH*2, 256, 0, stream>>>(dlt, ubuf, xdbc, Al, sumdvB, Hbuf);
    scan_pass2<<<SC/256, 256, 0, stream>>>(sumdvB, Al, Hbuf);
    scan_pass3<<<BATCH*CCH*2, 256, 0, stream>>>(dlt, ubuf, xzb, xdbc, Al, Dp + i*DI, Hbuf);

    // h += g @ W_out^T  [M,256] f32 accumulate
    gemm_lds<2><<<dim3(DM/128, MROWS/128), 256, 0, stream>>>(ubuf, Wo, hbuf, nullptr, DM, DI);
  }

  transpose_out<<<dim3(SEQ/32, DM/32, BATCH), dim3(32,8), 0, stream>>>(hbuf, out);
}

// Round 8
// 1630.174 us; speedup vs baseline: 7.9533x; 1.1163x over previous
//
#include <hip/hip_runtime.h>

#define BATCH 8
#define SEQ   4096
#define DM    256
#define DI    512
#define DS    16
#define DTR   16
#define NL    6
#define MROWS (BATCH*SEQ)   // 32768
#define CCH   64            // scan chunks
#define CL    (SEQ/CCH)     // 64 steps per chunk
#define SC    (BATCH*DI*DS) // 65536 per-chunk scan states

typedef float  f32x4 __attribute__((ext_vector_type(4)));
typedef __bf16 bf16x8 __attribute__((ext_vector_type(8)));
typedef unsigned short u16x8 __attribute__((ext_vector_type(8)));

__device__ __forceinline__ float bf2f(unsigned short b){
  unsigned u = ((unsigned)b) << 16;
  return __builtin_bit_cast(float, u);
}
__device__ __forceinline__ unsigned short f2bf(float f){
  unsigned u = __builtin_bit_cast(unsigned, f);
  unsigned r = u + 0x7FFFu + ((u >> 16) & 1u);
  return (unsigned short)(r >> 16);
}

#define ASEL(i) ((i)<4?Aq0[(i)&3]:(i)<8?Aq1[(i)&3]:(i)<12?Aq2[(i)&3]:Aq3[(i)&3])
#define BSEL(i) ((i)<4?B0[(i)&3]:(i)<8?B1[(i)&3]:(i)<12?B2[(i)&3]:B3[(i)&3])
#define CSEL(i) ((i)<4?C0[(i)&3]:(i)<8?C1[(i)&3]:(i)<12?C2[(i)&3]:C3[(i)&3])

// ---------------- transpose x [B,256,L] f32 -> h [(b*L+l)*256+c] f32 ----------------
__global__ void transpose_in(const float* __restrict__ x, float* __restrict__ h){
  __shared__ float tile[32][33];
  int b = blockIdx.z;
  int l0 = blockIdx.x*32, c0 = blockIdx.y*32;
  int tx = threadIdx.x, ty = threadIdx.y;
  #pragma unroll
  for (int i=0;i<4;i++)
    tile[ty+8*i][tx] = x[((size_t)(b*DM + c0+ty+8*i))*SEQ + l0 + tx];
  __syncthreads();
  #pragma unroll
  for (int i=0;i<4;i++)
    h[((size_t)(b*SEQ + l0+ty+8*i))*DM + c0 + tx] = tile[tx][ty+8*i];
}

// ---------------- transpose h -> out [B,256,L] ----------------
__global__ void transpose_out(const float* __restrict__ h, float* __restrict__ out){
  __shared__ float tile[32][33];
  int b = blockIdx.z;
  int l0 = blockIdx.x*32, c0 = blockIdx.y*32;
  int tx = threadIdx.x, ty = threadIdx.y;
  #pragma unroll
  for (int i=0;i<4;i++)
    tile[ty+8*i][tx] = h[((size_t)(b*SEQ + l0+ty+8*i))*DM + c0 + tx];
  __syncthreads();
  #pragma unroll
  for (int i=0;i<4;i++)
    out[((size_t)(b*DM + c0+ty+8*i))*SEQ + l0 + tx] = tile[tx][ty+8*i];
}

// ---------------- f32 -> bf16 convert ----------------
__global__ void cvt_bf16(const float* __restrict__ in, unsigned short* __restrict__ out, int n){
  int i = blockIdx.x*256 + threadIdx.x;
  if (i < n) out[i] = f2bf(in[i]);
}

// ---------------- W_eff[l][d][k] = sum_r W_dt[l][d][r] * W_x[l][r][k], bf16 out ----------------
__global__ void weff_kernel(const float* __restrict__ Wdt, const float* __restrict__ Wx,
                            unsigned short* __restrict__ Weff){
  int idx = blockIdx.x*256 + threadIdx.x;   // over NL*512*512
  int l = idx >> 18;
  int r = idx & 262143;
  int d = r >> 9, k = r & 511;
  const float* wd = Wdt + (size_t)l*DI*DTR + d*DTR;
  const float* wx = Wx  + (size_t)l*48*DI + k;
  float acc = 0.f;
  #pragma unroll
  for (int j=0;j<16;j++) acc += wd[j]*wx[(size_t)j*DI];
  Weff[idx] = f2bf(acc);
}

// ---------------- LayerNorm over 256 channels, one wave per row, bf16 out ----------------
__global__ void ln_kernel(const float* __restrict__ h, const float* __restrict__ g,
                          const float* __restrict__ bta, unsigned short* __restrict__ out){
  int wave = threadIdx.x >> 6, lane = threadIdx.x & 63;
  size_t row = (size_t)blockIdx.x*4 + wave;
  const float* hr = h + row*DM;
  f32x4 v = *reinterpret_cast<const f32x4*>(hr + lane*4);
  float s  = v.x + v.y + v.z + v.w;
  float sq = v.x*v.x + v.y*v.y + v.z*v.z + v.w*v.w;
  #pragma unroll
  for (int off=32; off; off>>=1){
    s  += __shfl_xor(s,  off, 64);
    sq += __shfl_xor(sq, off, 64);
  }
  float mean = s * (1.f/DM);
  float var  = sq * (1.f/DM) - mean*mean;
  float rstd = rsqrtf(var + 1e-5f);
  f32x4 gg = *reinterpret_cast<const f32x4*>(g   + lane*4);
  f32x4 bb = *reinterpret_cast<const f32x4*>(bta + lane*4);
  unsigned short* o = out + row*DM + lane*4;
  o[0] = f2bf((v.x-mean)*rstd*gg.x + bb.x);
  o[1] = f2bf((v.y-mean)*rstd*gg.y + bb.y);
  o[2] = f2bf((v.z-mean)*rstd*gg.z + bb.z);
  o[3] = f2bf((v.w-mean)*rstd*gg.w + bb.w);
}

// ======== LDS double-buffered bf16 MFMA GEMM (m97 structure) ========
// C[M,N] = A[M,K] @ W[N,K]^T, 128x128 block tile, BK=32, 4 waves (2x2), 4x4 frags/wave
// OUTMODE 0: f32 store, 1: bf16 store, 2: f32 accumulate, 3: softplus(acc+bias) bf16 store
template<int OUTMODE>
__global__ __launch_bounds__(256) void gemm_lds(const unsigned short* __restrict__ A,
                                                const unsigned short* __restrict__ W,
                                                void* __restrict__ Cout,
                                                const float* __restrict__ bias, int N, int K){
  __shared__ __align__(16) unsigned short lds[2][2][128*32];
  int tid  = threadIdx.x;
  int wave = tid >> 6, lane = tid & 63;
  int wr = wave >> 1, wc = wave & 1;
  int mblock = blockIdx.y*128, nblock = blockIdx.x*128;
  int l15 = lane & 15, ks = (lane >> 4) * 8;
  int srow = lane >> 2;        // staging: 4 lanes per row
  int scol = (lane & 3) * 8;   // ushort offset within row

  f32x4 acc[4][4] = {};

  auto stage = [&](int buf, int k0){
    #pragma unroll
    for (int j=0; j<2; j++){
      int stripe = 4*j + wave;
      int rA = mblock + 16*stripe + srow;
      const unsigned short* ga = A + (size_t)rA*K + k0 + scol;
      __builtin_amdgcn_global_load_lds(ga, &lds[buf][0][stripe*512], 16, 0, 0);
      int rB = nblock + 16*stripe + srow; if (rB >= N) rB = N-1;
      const unsigned short* gb = W + (size_t)rB*K + k0 + scol;
      __builtin_amdgcn_global_load_lds(gb, &lds[buf][1][stripe*512], 16, 0, 0);
    }
  };

  stage(0, 0);
  __syncthreads();                 // drains vmcnt before first ds_read

  int nsteps = K >> 5;
  for (int s=0; s<nsteps; s++){
    int buf = s & 1;
    if (s+1 < nsteps) stage(buf^1, (s+1)*32);
    bf16x8 af[4], bfr[4];
    #pragma unroll
    for (int mf=0; mf<4; mf++)
      af[mf] = *(const bf16x8*)&lds[buf][0][(wr*64 + mf*16 + l15)*32 + ks];
    #pragma unroll
    for (int nf=0; nf<4; nf++)
      bfr[nf] = *(const bf16x8*)&lds[buf][1][(wc*64 + nf*16 + l15)*32 + ks];
    #pragma unroll
    for (int mf=0; mf<4; mf++)
      #pragma unroll
      for (int nf=0; nf<4; nf++)
        acc[mf][nf] = __builtin_amdgcn_mfma_f32_16x16x32_bf16(af[mf], bfr[nf], acc[mf][nf], 0,0,0);
    __syncthreads();               // drain staged tile + protect buf reuse
  }

  int rb = mblock + wr*64 + (lane >> 4)*4;
  #pragma unroll
  for (int mf=0; mf<4; mf++){
    #pragma unroll
    for (int nf=0; nf<4; nf++){
      int col = nblock + wc*64 + nf*16 + l15;
      if (col < N){
        float bv = (OUTMODE == 3) ? bias[col] : 0.f;
        #pragma unroll
        for (int j=0; j<4; j++){
          size_t idx = (size_t)(rb + mf*16 + j)*N + col;
          if (OUTMODE == 0)      ((float*)Cout)[idx] = acc[mf][nf][j];
          else if (OUTMODE == 1) ((unsigned short*)Cout)[idx] = f2bf(acc[mf][nf][j]);
          else if (OUTMODE == 2) ((float*)Cout)[idx] += acc[mf][nf][j];
          else {
            float v = acc[mf][nf][j] + bv;
            float sp = fmaxf(v, 0.f) + __logf(1.f + __expf(-fabsf(v)));
            ((unsigned short*)Cout)[idx] = f2bf(sp);
          }
        }
      }
    }
  }
}

// ---------------- depthwise causal conv(4) + bias + SiLU, 8 channels/thread ----------------
__global__ void conv_kernel(const unsigned short* __restrict__ xz, const float* __restrict__ cw,
                            const float* __restrict__ cb, unsigned short* __restrict__ u){
  size_t idx = (size_t)blockIdx.x*256 + threadIdx.x;  // over MROWS*64
  int d0 = (int)(idx & 63) * 8;
  size_t row = idx >> 6;
  int l = (int)(row & (SEQ-1));
  const unsigned short* base = xz + row*1024 + d0;
  u16x8 v3 = *(const u16x8*)(base);
  u16x8 v2 = (l>=1) ? *(const u16x8*)(base - 1024) : (u16x8)(0);
  u16x8 v1 = (l>=2) ? *(const u16x8*)(base - 2048) : (u16x8)(0);
  u16x8 v0 = (l>=3) ? *(const u16x8*)(base - 3072) : (u16x8)(0);
  u16x8 out;
  #pragma unroll
  for (int j=0; j<8; j++){
    int d = d0 + j;
    f32x4 w = *reinterpret_cast<const f32x4*>(cw + d*4);
    float acc = cb[d] + bf2f(v3[j])*w.w + bf2f(v2[j])*w.z
                      + bf2f(v1[j])*w.y + bf2f(v0[j])*w.x;
    float s = acc / (1.f + __expf(-acc));
    out[j] = f2bf(s);
  }
  *(u16x8*)(u + row*512 + d0) = out;
}

// ================= SSM chunked scan, lane-per-d layout =================
// xdbc layout: [M][32] f32: cols 0..15 = B, 16..31 = C
template<bool POW>
__device__ __forceinline__ void pass1_body(
    const unsigned short* dptr, const unsigned short* uptr, const float* bptr,
    const float* A, float* h, float& sumdv){
  #pragma unroll 2
  for (int l=0; l<CL; l++){
    float dv = bf2f(dptr[(size_t)l*512]);
    float uv = bf2f(uptr[(size_t)l*512]);
    const float* br = bptr + (size_t)l*32;
    f32x4 B0 = *(const f32x4*)(br + 0);
    f32x4 B1 = *(const f32x4*)(br + 4);
    f32x4 B2 = *(const f32x4*)(br + 8);
    f32x4 B3 = *(const f32x4*)(br + 12);
    float t = dv*uv;
    sumdv += dv;
    if (POW){
      float a0 = __expf(dv*A[0]);
      float ap = 1.f;
      #pragma unroll
      for (int i=0;i<16;i++){ ap *= a0; h[i] = ap*h[i] + t*BSEL(i); }
    } else {
      #pragma unroll
      for (int i=0;i<16;i++){ float a = __expf(dv*A[i]); h[i] = a*h[i] + t*BSEL(i); }
    }
  }
}

__global__ void __launch_bounds__(256) scan_pass1(
    const unsigned short* __restrict__ dlt, const unsigned short* __restrict__ u,
    const float* __restrict__ xdb, const float* __restrict__ Alog,
    float* __restrict__ sumdvB, float* __restrict__ Hbuf){
  int bid = blockIdx.x;               // ((b*CCH)+c)*2 + half
  int half = bid & 1;
  int c = (bid >> 1) & (CCH-1);
  int b = bid >> 7;
  int wave = threadIdx.x >> 6, lane = threadIdx.x & 63;
  int d = half*256 + wave*64 + lane;
  const float* ar = Alog + d*16;
  f32x4 Aq0 = *(const f32x4*)(ar+0), Aq1 = *(const f32x4*)(ar+4);
  f32x4 Aq2 = *(const f32x4*)(ar+8), Aq3 = *(const f32x4*)(ar+12);
  float A[16];
  #pragma unroll
  for (int i=0;i<16;i++) A[i] = -__expf(ASEL(i));
  bool pw = true;
  #pragma unroll
  for (int i=1;i<16;i++) pw = pw && (fabsf(A[i] - (float)(i+1)*A[0]) <= 1e-3f*fabsf(A[i]));
  float h[16];
  #pragma unroll
  for (int i=0;i<16;i++) h[i] = 0.f;
  float sumdv = 0.f;
  size_t rowbase = (size_t)b*SEQ + (size_t)c*CL;
  const unsigned short* dptr = dlt + rowbase*512 + d;
  const unsigned short* uptr = u   + rowbase*512 + d;
  const float*          bptr = xdb + rowbase*32;
  if (pw) pass1_body<true >(dptr, uptr, bptr, A, h, sumdv);
  else    pass1_body<false>(dptr, uptr, bptr, A, h, sumdv);
  size_t o = (size_t)(c*BATCH + b)*512 + d;
  sumdvB[o] = sumdv;
  float* Hp = Hbuf + o*16;
  *(f32x4*)(Hp+ 0) = f32x4{h[0],h[1],h[2],h[3]};
  *(f32x4*)(Hp+ 4) = f32x4{h[4],h[5],h[6],h[7]};
  *(f32x4*)(Hp+ 8) = f32x4{h[8],h[9],h[10],h[11]};
  *(f32x4*)(Hp+12) = f32x4{h[12],h[13],h[14],h[15]};
}

// pass2: thread per (b,d,n): serial combine over chunks; Hbuf[c] := h_init(c)
__global__ void __launch_bounds__(256) scan_pass2(
    const float* __restrict__ sumdvB, const float* __restrict__ Alog,
    float* __restrict__ Hbuf){
  int gid = blockIdx.x*256 + threadIdx.x;   // b*8192 + d*16 + n
  float A = -__expf(Alog[gid & 8191]);
  float H = 0.f;
  for (int c=0; c<CCH; c++){
    float s  = sumdvB[(size_t)c*(BATCH*DI) + (gid>>4)];
    size_t o = (size_t)c*SC + gid;
    float hf = Hbuf[o];
    Hbuf[o] = H;
    H = __expf(A*s)*H + hf;
  }
}

// pass3: re-run chunk from h_init; y = C.h + D*u; fused gate: g = y*silu(z); bf16 g over u
template<bool POW>
__device__ __forceinline__ void pass3_body(
    const unsigned short* dptr, unsigned short* uptr, const unsigned short* zptr,
    const float* bptr, const float* A, float* h, float Dd){
  #pragma unroll 2
  for (int l=0; l<CL; l++){
    float dv = bf2f(dptr[(size_t)l*512]);
    float uv = bf2f(uptr[(size_t)l*512]);
    float zv = bf2f(zptr[(size_t)l*1024]);
    const float* br = bptr + (size_t)l*32;
    f32x4 B0 = *(const f32x4*)(br + 0);
    f32x4 B1 = *(const f32x4*)(br + 4);
    f32x4 B2 = *(const f32x4*)(br + 8);
    f32x4 B3 = *(const f32x4*)(br + 12);
    f32x4 C0 = *(const f32x4*)(br + 16);
    f32x4 C1 = *(const f32x4*)(br + 20);
    f32x4 C2 = *(const f32x4*)(br + 24);
    f32x4 C3 = *(const f32x4*)(br + 28);
    float t = dv*uv;
    float p0=0.f,p1=0.f,p2=0.f,p3=0.f;
    if (POW){
      float a0 = __expf(dv*A[0]);
      float ap = 1.f;
      #pragma unroll
      for (int i=0;i<16;i++){
        ap *= a0;
        h[i] = ap*h[i] + t*BSEL(i);
        float hp = h[i]*CSEL(i);
        if ((i&3)==0) p0 += hp; else if ((i&3)==1) p1 += hp; else if ((i&3)==2) p2 += hp; else p3 += hp;
      }
    } else {
      #pragma unroll
      for (int i=0;i<16;i++){
        float a = __expf(dv*A[i]);
        h[i] = a*h[i] + t*BSEL(i);
        float hp = h[i]*CSEL(i);
        if ((i&3)==0) p0 += hp; else if ((i&3)==1) p1 += hp; else if ((i&3)==2) p2 += hp; else p3 += hp;
      }
    }
    float y = (p0+p1) + (p2+p3) + Dd*uv;
    float g = y * (zv / (1.f + __expf(-zv)));
    uptr[(size_t)l*512] = f2bf(g);
  }
}

__global__ void __launch_bounds__(256) scan_pass3(
    const unsigned short* __restrict__ dlt, unsigned short* __restrict__ u,
    const unsigned short* __restrict__ xz, const float* __restrict__ xdb,
    const float* __restrict__ Alog, const float* __restrict__ Dp,
    const float* __restrict__ Hbuf){
  int bid = blockIdx.x;
  int half = bid & 1;
  int c = (bid >> 1) & (CCH-1);
  int b = bid >> 7;
  int wave = threadIdx.x >> 6, lane = threadIdx.x & 63;
  int d = half*256 + wave*64 + lane;
  const float* ar = Alog + d*16;
  f32x4 Aq0 = *(const f32x4*)(ar+0), Aq1 = *(const f32x4*)(ar+4);
  f32x4 Aq2 = *(const f32x4*)(ar+8), Aq3 = *(const f32x4*)(ar+12);
  float A[16];
  #pragma unroll
  for (int i=0;i<16;i++) A[i] = -__expf(ASEL(i));
  bool pw = true;
  #pragma unroll
  for (int i=1;i<16;i++) pw = pw && (fabsf(A[i] - (float)(i+1)*A[0]) <= 1e-3f*fabsf(A[i]));
  float Dd = Dp[d];
  size_t o = (size_t)(c*BATCH + b)*512 + d;
  const float* Hp = Hbuf + o*16;
  f32x4 h0 = *(const f32x4*)(Hp+0), h1 = *(const f32x4*)(Hp+4);
  f32x4 h2 = *(const f32x4*)(Hp+8), h3 = *(const f32x4*)(Hp+12);
  float h[16] = {h0.x,h0.y,h0.z,h0.w, h1.x,h1.y,h1.z,h1.w,
                 h2.x,h2.y,h2.z,h2.w, h3.x,h3.y,h3.z,h3.w};
  size_t rowbase = (size_t)b*SEQ + (size_t)c*CL;
  const unsigned short* dptr = dlt + rowbase*512 + d;
  unsigned short*       uptr = u   + rowbase*512 + d;
  const unsigned short* zptr = xz  + rowbase*1024 + 512 + d;
  const float*          bptr = xdb + rowbase*32;
  if (pw) pass3_body<true >(dptr, uptr, zptr, bptr, A, h, Dd);
  else    pass3_body<false>(dptr, uptr, zptr, bptr, A, h, Dd);
}

extern "C" void kernel_launch(void* const* d_in, const int* in_sizes, int n_in,
                              void* d_out, int out_size, void* d_ws, size_t ws_size,
                              hipStream_t stream){
  (void)in_sizes; (void)n_in; (void)out_size; (void)ws_size;
  const float* x      = (const float*)d_in[0];
  const float* W_in   = (const float*)d_in[1];
  const float* conv_w = (const float*)d_in[2];
  const float* conv_b = (const float*)d_in[3];
  const float* W_x    = (const float*)d_in[4];
  const float* W_dt   = (const float*)d_in[5];
  const float* b_dt   = (const float*)d_in[6];
  const float* A_log  = (const float*)d_in[7];
  const float* Dp     = (const float*)d_in[8];
  const float* W_out  = (const float*)d_in[9];
  const float* ln_g   = (const float*)d_in[10];
  const float* ln_b   = (const float*)d_in[11];
  float* out = (float*)d_out;

  // workspace carve-up (~196 MB)
  char* p = (char*)d_ws;
  auto alloc = [&](size_t bytes)->char*{
    char* r = p; p += (bytes + 255) & ~(size_t)255; return r;
  };
  float*          hbuf   = (float*)alloc((size_t)MROWS*DM*4);           // 33.5 MB residual f32
  unsigned short* xzb    = (unsigned short*)alloc((size_t)MROWS*1024*2);// 67 MB
  unsigned short* ubuf   = (unsigned short*)alloc((size_t)MROWS*DI*2);  // 33.5 MB (u, then gated g)
  unsigned short* lnb    = (unsigned short*)alloc((size_t)MROWS*DI*2);  // 33.5 MB shared: lnb / delta
  unsigned short* dlt    = lnb;                                         // alias (disjoint live ranges)
  float*          xdbc   = (float*)alloc((size_t)MROWS*32*4);           // 4.2 MB (B,C)
  unsigned short* WinB   = (unsigned short*)alloc((size_t)NL*1024*DM*2);// 3.1 MB
  unsigned short* WxB    = (unsigned short*)alloc((size_t)NL*48*DI*2);  // 0.3 MB
  unsigned short* WoutB  = (unsigned short*)alloc((size_t)NL*DM*DI*2);  // 1.6 MB
  unsigned short* WeffB  = (unsigned short*)alloc((size_t)NL*DI*DI*2);  // 3.1 MB
  float*          sumdvB = (float*)alloc((size_t)CCH*BATCH*DI*4);       // 1.05 MB
  float*          Hbuf   = (float*)alloc((size_t)CCH*SC*4);             // 16.8 MB

  // weight conversion + W_eff precompute
  {
    int n1 = NL*1024*DM;  cvt_bf16<<<(n1+255)/256, 256, 0, stream>>>(W_in,  WinB,  n1);
    int n2 = NL*48*DI;    cvt_bf16<<<(n2+255)/256, 256, 0, stream>>>(W_x,   WxB,   n2);
    int n3 = NL*DM*DI;    cvt_bf16<<<(n3+255)/256, 256, 0, stream>>>(W_out, WoutB, n3);
    weff_kernel<<<NL*DI*DI/256, 256, 0, stream>>>(W_dt, W_x, WeffB);
  }

  transpose_in<<<dim3(SEQ/32, DM/32, BATCH), dim3(32,8), 0, stream>>>(x, hbuf);

  for (int i=0; i<NL; i++){
    const unsigned short* Wi = WinB  + (size_t)i*1024*DM;
    const unsigned short* Wx = WxB   + (size_t)i*48*DI + 16*DI;  // B,C rows only
    const unsigned short* Wo = WoutB + (size_t)i*DM*DI;
    const unsigned short* We = WeffB + (size_t)i*DI*DI;
    const float* Al = A_log + (size_t)i*DI*DS;

    ln_kernel<<<MROWS/4, 256, 0, stream>>>(hbuf, ln_g + i*DM, ln_b + i*DM, lnb);

    // xz = ln @ W_in^T  [M,1024] bf16
    gemm_lds<1><<<dim3(1024/128, MROWS/128), 256, 0, stream>>>(lnb, Wi, xzb, nullptr, 1024, DM);

    conv_kernel<<<MROWS*64/256, 256, 0, stream>>>(xzb, conv_w + (size_t)i*DI*4,
                                                  conv_b + i*DI, ubuf);

    // xdbc = u @ Wx[16:48]^T  [M,32] f32 (B,C)
    gemm_lds<0><<<dim3(1, MROWS/128), 256, 0, stream>>>(ubuf, Wx, xdbc, nullptr, 32, DI);

    // delta = softplus(u @ W_eff^T + b_dt)  [M,512] bf16
    gemm_lds<3><<<dim3(DI/128, MROWS/128), 256, 0, stream>>>(ubuf, We, dlt, b_dt + i*DI, DI, DI);

    scan_pass1<<<BATCH*CCH*2, 256, 0, stream>>>(dlt, ubuf, xdbc, Al, sumdvB, Hbuf);
    scan_pass2<<<SC/256, 256, 0, stream>>>(sumdvB, Al, Hbuf);
    scan_pass3<<<BATCH*CCH*2, 256, 0, stream>>>(dlt, ubuf, xzb, xdbc, Al, Dp + i*DI, Hbuf);

    // h += g @ W_out^T  [M,256] f32 accumulate
    gemm_lds<2><<<dim3(DM/128, MROWS/128), 256, 0, stream>>>(ubuf, Wo, hbuf, nullptr, DM, DI);
  }

  transpose_out<<<dim3(SEQ/32, DM/32, BATCH), dim3(32,8), 0, stream>>>(hbuf, out);
}

// Round 9
// 1618.302 us; speedup vs baseline: 8.0117x; 1.0073x over previous
//
#include <hip/hip_runtime.h>

#define BATCH 8
#define SEQ   4096
#define DM    256
#define DI    512
#define DS    16
#define DTR   16
#define NL    6
#define MROWS (BATCH*SEQ)   // 32768
#define CCH   128           // scan chunks
#define CL    (SEQ/CCH)     // 32 steps per chunk
#define SC    (BATCH*DI*DS) // 65536 per-chunk scan states

typedef float  f32x4 __attribute__((ext_vector_type(4)));
typedef __bf16 bf16x8 __attribute__((ext_vector_type(8)));
typedef unsigned short u16x8 __attribute__((ext_vector_type(8)));

__device__ __forceinline__ float bf2f(unsigned short b){
  unsigned u = ((unsigned)b) << 16;
  return __builtin_bit_cast(float, u);
}
__device__ __forceinline__ unsigned short f2bf(float f){
  unsigned u = __builtin_bit_cast(unsigned, f);
  unsigned r = u + 0x7FFFu + ((u >> 16) & 1u);
  return (unsigned short)(r >> 16);
}

#define ASEL(i) ((i)<4?Aq0[(i)&3]:(i)<8?Aq1[(i)&3]:(i)<12?Aq2[(i)&3]:Aq3[(i)&3])
#define BSEL(i) ((i)<4?B0[(i)&3]:(i)<8?B1[(i)&3]:(i)<12?B2[(i)&3]:B3[(i)&3])
#define CSEL(i) ((i)<4?C0[(i)&3]:(i)<8?C1[(i)&3]:(i)<12?C2[(i)&3]:C3[(i)&3])

// depth-4 power tree: ap[i] = a1^(i+1), 14 muls
__device__ __forceinline__ void powers16(float a1, float* ap){
  float a2=a1*a1, a4=a2*a2, a8=a4*a4;
  ap[0]=a1;      ap[1]=a2;      ap[2]=a2*a1;   ap[3]=a4;
  ap[4]=a4*a1;   ap[5]=a4*a2;   ap[6]=a4*ap[2];ap[7]=a8;
  ap[8]=a8*a1;   ap[9]=a8*a2;   ap[10]=a8*ap[2];ap[11]=a8*a4;
  ap[12]=a8*ap[4];ap[13]=a8*ap[5];ap[14]=a8*ap[6];ap[15]=a8*a8;
}

// ---------------- transpose x [B,256,L] f32 -> h [(b*L+l)*256+c] f32 ----------------
__global__ void transpose_in(const float* __restrict__ x, float* __restrict__ h){
  __shared__ float tile[32][33];
  int b = blockIdx.z;
  int l0 = blockIdx.x*32, c0 = blockIdx.y*32;
  int tx = threadIdx.x, ty = threadIdx.y;
  #pragma unroll
  for (int i=0;i<4;i++)
    tile[ty+8*i][tx] = x[((size_t)(b*DM + c0+ty+8*i))*SEQ + l0 + tx];
  __syncthreads();
  #pragma unroll
  for (int i=0;i<4;i++)
    h[((size_t)(b*SEQ + l0+ty+8*i))*DM + c0 + tx] = tile[tx][ty+8*i];
}

// ---------------- transpose h -> out [B,256,L] ----------------
__global__ void transpose_out(const float* __restrict__ h, float* __restrict__ out){
  __shared__ float tile[32][33];
  int b = blockIdx.z;
  int l0 = blockIdx.x*32, c0 = blockIdx.y*32;
  int tx = threadIdx.x, ty = threadIdx.y;
  #pragma unroll
  for (int i=0;i<4;i++)
    tile[ty+8*i][tx] = h[((size_t)(b*SEQ + l0+ty+8*i))*DM + c0 + tx];
  __syncthreads();
  #pragma unroll
  for (int i=0;i<4;i++)
    out[((size_t)(b*DM + c0+ty+8*i))*SEQ + l0 + tx] = tile[tx][ty+8*i];
}

// ---------------- f32 -> bf16 convert ----------------
__global__ void cvt_bf16(const float* __restrict__ in, unsigned short* __restrict__ out, int n){
  int i = blockIdx.x*256 + threadIdx.x;
  if (i < n) out[i] = f2bf(in[i]);
}

// ---------------- W_eff[l][d][k] = sum_r W_dt[l][d][r] * W_x[l][r][k], bf16 out ----------------
__global__ void weff_kernel(const float* __restrict__ Wdt, const float* __restrict__ Wx,
                            unsigned short* __restrict__ Weff){
  int idx = blockIdx.x*256 + threadIdx.x;   // over NL*512*512
  int l = idx >> 18;
  int r = idx & 262143;
  int d = r >> 9, k = r & 511;
  const float* wd = Wdt + (size_t)l*DI*DTR + d*DTR;
  const float* wx = Wx  + (size_t)l*48*DI + k;
  float acc = 0.f;
  #pragma unroll
  for (int j=0;j<16;j++) acc += wd[j]*wx[(size_t)j*DI];
  Weff[idx] = f2bf(acc);
}

// ---------------- LayerNorm over 256 channels, one wave per row, bf16 out ----------------
__global__ void ln_kernel(const float* __restrict__ h, const float* __restrict__ g,
                          const float* __restrict__ bta, unsigned short* __restrict__ out){
  int wave = threadIdx.x >> 6, lane = threadIdx.x & 63;
  size_t row = (size_t)blockIdx.x*4 + wave;
  const float* hr = h + row*DM;
  f32x4 v = *reinterpret_cast<const f32x4*>(hr + lane*4);
  float s  = v.x + v.y + v.z + v.w;
  float sq = v.x*v.x + v.y*v.y + v.z*v.z + v.w*v.w;
  #pragma unroll
  for (int off=32; off; off>>=1){
    s  += __shfl_xor(s,  off, 64);
    sq += __shfl_xor(sq, off, 64);
  }
  float mean = s * (1.f/DM);
  float var  = sq * (1.f/DM) - mean*mean;
  float rstd = rsqrtf(var + 1e-5f);
  f32x4 gg = *reinterpret_cast<const f32x4*>(g   + lane*4);
  f32x4 bb = *reinterpret_cast<const f32x4*>(bta + lane*4);
  unsigned short* o = out + row*DM + lane*4;
  o[0] = f2bf((v.x-mean)*rstd*gg.x + bb.x);
  o[1] = f2bf((v.y-mean)*rstd*gg.y + bb.y);
  o[2] = f2bf((v.z-mean)*rstd*gg.z + bb.z);
  o[3] = f2bf((v.w-mean)*rstd*gg.w + bb.w);
}

// ======== LDS double-buffered bf16 MFMA GEMM (m97 structure) ========
// C[M,N] = A[M,K] @ W[N,K]^T, 128x128 block tile, BK=32, 4 waves (2x2), 4x4 frags/wave
// OUTMODE 0: f32 store, 1: bf16 store, 2: f32 accumulate, 3: softplus(acc+bias) bf16 store
template<int OUTMODE>
__global__ __launch_bounds__(256) void gemm_lds(const unsigned short* __restrict__ A,
                                                const unsigned short* __restrict__ W,
                                                void* __restrict__ Cout,
                                                const float* __restrict__ bias, int N, int K){
  __shared__ __align__(16) unsigned short lds[2][2][128*32];
  int tid  = threadIdx.x;
  int wave = tid >> 6, lane = tid & 63;
  int wr = wave >> 1, wc = wave & 1;
  int mblock = blockIdx.y*128, nblock = blockIdx.x*128;
  int l15 = lane & 15, ks = (lane >> 4) * 8;
  int srow = lane >> 2;        // staging: 4 lanes per row
  int scol = (lane & 3) * 8;   // ushort offset within row

  f32x4 acc[4][4] = {};

  auto stage = [&](int buf, int k0){
    #pragma unroll
    for (int j=0; j<2; j++){
      int stripe = 4*j + wave;
      int rA = mblock + 16*stripe + srow;
      const unsigned short* ga = A + (size_t)rA*K + k0 + scol;
      __builtin_amdgcn_global_load_lds(ga, &lds[buf][0][stripe*512], 16, 0, 0);
      int rB = nblock + 16*stripe + srow; if (rB >= N) rB = N-1;
      const unsigned short* gb = W + (size_t)rB*K + k0 + scol;
      __builtin_amdgcn_global_load_lds(gb, &lds[buf][1][stripe*512], 16, 0, 0);
    }
  };

  stage(0, 0);
  __syncthreads();                 // drains vmcnt before first ds_read

  int nsteps = K >> 5;
  for (int s=0; s<nsteps; s++){
    int buf = s & 1;
    if (s+1 < nsteps) stage(buf^1, (s+1)*32);
    bf16x8 af[4], bfr[4];
    #pragma unroll
    for (int mf=0; mf<4; mf++)
      af[mf] = *(const bf16x8*)&lds[buf][0][(wr*64 + mf*16 + l15)*32 + ks];
    #pragma unroll
    for (int nf=0; nf<4; nf++)
      bfr[nf] = *(const bf16x8*)&lds[buf][1][(wc*64 + nf*16 + l15)*32 + ks];
    #pragma unroll
    for (int mf=0; mf<4; mf++)
      #pragma unroll
      for (int nf=0; nf<4; nf++)
        acc[mf][nf] = __builtin_amdgcn_mfma_f32_16x16x32_bf16(af[mf], bfr[nf], acc[mf][nf], 0,0,0);
    __syncthreads();               // drain staged tile + protect buf reuse
  }

  int rb = mblock + wr*64 + (lane >> 4)*4;
  #pragma unroll
  for (int mf=0; mf<4; mf++){
    #pragma unroll
    for (int nf=0; nf<4; nf++){
      int col = nblock + wc*64 + nf*16 + l15;
      if (col < N){
        float bv = (OUTMODE == 3) ? bias[col] : 0.f;
        #pragma unroll
        for (int j=0; j<4; j++){
          size_t idx = (size_t)(rb + mf*16 + j)*N + col;
          if (OUTMODE == 0)      ((float*)Cout)[idx] = acc[mf][nf][j];
          else if (OUTMODE == 1) ((unsigned short*)Cout)[idx] = f2bf(acc[mf][nf][j]);
          else if (OUTMODE == 2) ((float*)Cout)[idx] += acc[mf][nf][j];
          else {
            float v = acc[mf][nf][j] + bv;
            float sp = fmaxf(v, 0.f) + __logf(1.f + __expf(-fabsf(v)));
            ((unsigned short*)Cout)[idx] = f2bf(sp);
          }
        }
      }
    }
  }
}

// ---------------- depthwise causal conv(4) + bias + SiLU, 8 channels/thread ----------------
__global__ void conv_kernel(const unsigned short* __restrict__ xz, const float* __restrict__ cw,
                            const float* __restrict__ cb, unsigned short* __restrict__ u){
  size_t idx = (size_t)blockIdx.x*256 + threadIdx.x;  // over MROWS*64
  int d0 = (int)(idx & 63) * 8;
  size_t row = idx >> 6;
  int l = (int)(row & (SEQ-1));
  const unsigned short* base = xz + row*1024 + d0;
  u16x8 v3 = *(const u16x8*)(base);
  u16x8 v2 = (l>=1) ? *(const u16x8*)(base - 1024) : (u16x8)(0);
  u16x8 v1 = (l>=2) ? *(const u16x8*)(base - 2048) : (u16x8)(0);
  u16x8 v0 = (l>=3) ? *(const u16x8*)(base - 3072) : (u16x8)(0);
  u16x8 out;
  #pragma unroll
  for (int j=0; j<8; j++){
    int d = d0 + j;
    f32x4 w = *reinterpret_cast<const f32x4*>(cw + d*4);
    float acc = cb[d] + bf2f(v3[j])*w.w + bf2f(v2[j])*w.z
                      + bf2f(v1[j])*w.y + bf2f(v0[j])*w.x;
    float s = acc / (1.f + __expf(-acc));
    out[j] = f2bf(s);
  }
  *(u16x8*)(u + row*512 + d0) = out;
}

// ================= SSM chunked scan, lane-per-d layout =================
// xdbc layout: [M][32] f32: cols 0..15 = B, 16..31 = C
template<bool POW>
__device__ __forceinline__ void pass1_body(
    const unsigned short* dptr, const unsigned short* uptr, const float* bptr,
    const float* A, float* h, float& sumdv){
  #pragma unroll 2
  for (int l=0; l<CL; l++){
    float dv = bf2f(dptr[(size_t)l*512]);
    float uv = bf2f(uptr[(size_t)l*512]);
    const float* br = bptr + (size_t)l*32;
    f32x4 B0 = *(const f32x4*)(br + 0);
    f32x4 B1 = *(const f32x4*)(br + 4);
    f32x4 B2 = *(const f32x4*)(br + 8);
    f32x4 B3 = *(const f32x4*)(br + 12);
    float t = dv*uv;
    sumdv += dv;
    if (POW){
      float ap[16];
      powers16(__expf(dv*A[0]), ap);
      #pragma unroll
      for (int i=0;i<16;i++){ h[i] = ap[i]*h[i] + t*BSEL(i); }
    } else {
      #pragma unroll
      for (int i=0;i<16;i++){ float a = __expf(dv*A[i]); h[i] = a*h[i] + t*BSEL(i); }
    }
  }
}

__global__ void __launch_bounds__(256) scan_pass1(
    const unsigned short* __restrict__ dlt, const unsigned short* __restrict__ u,
    const float* __restrict__ xdb, const float* __restrict__ Alog,
    float* __restrict__ sumdvB, unsigned short* __restrict__ Hbuf){
  int bid = blockIdx.x;               // ((b*CCH)+c)*2 + half
  int half = bid & 1;
  int c = (bid >> 1) & (CCH-1);
  int b = bid / (CCH*2);
  int wave = threadIdx.x >> 6, lane = threadIdx.x & 63;
  int d = half*256 + wave*64 + lane;
  const float* ar = Alog + d*16;
  f32x4 Aq0 = *(const f32x4*)(ar+0), Aq1 = *(const f32x4*)(ar+4);
  f32x4 Aq2 = *(const f32x4*)(ar+8), Aq3 = *(const f32x4*)(ar+12);
  float A[16];
  #pragma unroll
  for (int i=0;i<16;i++) A[i] = -__expf(ASEL(i));
  bool pw = true;
  #pragma unroll
  for (int i=1;i<16;i++) pw = pw && (fabsf(A[i] - (float)(i+1)*A[0]) <= 1e-3f*fabsf(A[i]));
  float h[16];
  #pragma unroll
  for (int i=0;i<16;i++) h[i] = 0.f;
  float sumdv = 0.f;
  size_t rowbase = (size_t)b*SEQ + (size_t)c*CL;
  const unsigned short* dptr = dlt + rowbase*512 + d;
  const unsigned short* uptr = u   + rowbase*512 + d;
  const float*          bptr = xdb + rowbase*32;
  if (pw) pass1_body<true >(dptr, uptr, bptr, A, h, sumdv);
  else    pass1_body<false>(dptr, uptr, bptr, A, h, sumdv);
  size_t o = (size_t)(c*BATCH + b)*512 + d;
  sumdvB[o] = sumdv;
  unsigned short* Hp = Hbuf + o*16;
  u16x8 h0, h1;
  #pragma unroll
  for (int i=0;i<8;i++){ h0[i] = f2bf(h[i]); h1[i] = f2bf(h[8+i]); }
  *(u16x8*)(Hp+0) = h0;
  *(u16x8*)(Hp+8) = h1;
}

// pass2: thread per (b,d,n): serial combine over chunks; Hbuf[c] := h_init(c)
__global__ void __launch_bounds__(256) scan_pass2(
    const float* __restrict__ sumdvB, const float* __restrict__ Alog,
    unsigned short* __restrict__ Hbuf){
  int gid = blockIdx.x*256 + threadIdx.x;   // b*8192 + d*16 + n
  float A = -__expf(Alog[gid & 8191]);
  float H = 0.f;
  for (int c=0; c<CCH; c++){
    float s  = sumdvB[(size_t)c*(BATCH*DI) + (gid>>4)];
    size_t o = (size_t)c*SC + gid;
    float hf = bf2f(Hbuf[o]);
    Hbuf[o] = f2bf(H);
    H = __expf(A*s)*H + hf;
  }
}

// pass3: re-run chunk from h_init; y = C.h + D*u; fused gate: g = y*silu(z); bf16 g over u
template<bool POW>
__device__ __forceinline__ void pass3_body(
    const unsigned short* dptr, unsigned short* uptr, const unsigned short* zptr,
    const float* bptr, const float* A, float* h, float Dd){
  #pragma unroll 2
  for (int l=0; l<CL; l++){
    float dv = bf2f(dptr[(size_t)l*512]);
    float uv = bf2f(uptr[(size_t)l*512]);
    float zv = bf2f(zptr[(size_t)l*1024]);
    const float* br = bptr + (size_t)l*32;
    f32x4 B0 = *(const f32x4*)(br + 0);
    f32x4 B1 = *(const f32x4*)(br + 4);
    f32x4 B2 = *(const f32x4*)(br + 8);
    f32x4 B3 = *(const f32x4*)(br + 12);
    f32x4 C0 = *(const f32x4*)(br + 16);
    f32x4 C1 = *(const f32x4*)(br + 20);
    f32x4 C2 = *(const f32x4*)(br + 24);
    f32x4 C3 = *(const f32x4*)(br + 28);
    float t = dv*uv;
    float p0=0.f,p1=0.f,p2=0.f,p3=0.f;
    if (POW){
      float ap[16];
      powers16(__expf(dv*A[0]), ap);
      #pragma unroll
      for (int i=0;i<16;i++){
        h[i] = ap[i]*h[i] + t*BSEL(i);
        float hp = h[i]*CSEL(i);
        if ((i&3)==0) p0 += hp; else if ((i&3)==1) p1 += hp; else if ((i&3)==2) p2 += hp; else p3 += hp;
      }
    } else {
      #pragma unroll
      for (int i=0;i<16;i++){
        float a = __expf(dv*A[i]);
        h[i] = a*h[i] + t*BSEL(i);
        float hp = h[i]*CSEL(i);
        if ((i&3)==0) p0 += hp; else if ((i&3)==1) p1 += hp; else if ((i&3)==2) p2 += hp; else p3 += hp;
      }
    }
    float y = (p0+p1) + (p2+p3) + Dd*uv;
    float g = y * (zv / (1.f + __expf(-zv)));
    uptr[(size_t)l*512] = f2bf(g);
  }
}

__global__ void __launch_bounds__(256) scan_pass3(
    const unsigned short* __restrict__ dlt, unsigned short* __restrict__ u,
    const unsigned short* __restrict__ xz, const float* __restrict__ xdb,
    const float* __restrict__ Alog, const float* __restrict__ Dp,
    const unsigned short* __restrict__ Hbuf){
  int bid = blockIdx.x;
  int half = bid & 1;
  int c = (bid >> 1) & (CCH-1);
  int b = bid / (CCH*2);
  int wave = threadIdx.x >> 6, lane = threadIdx.x & 63;
  int d = half*256 + wave*64 + lane;
  const float* ar = Alog + d*16;
  f32x4 Aq0 = *(const f32x4*)(ar+0), Aq1 = *(const f32x4*)(ar+4);
  f32x4 Aq2 = *(const f32x4*)(ar+8), Aq3 = *(const f32x4*)(ar+12);
  float A[16];
  #pragma unroll
  for (int i=0;i<16;i++) A[i] = -__expf(ASEL(i));
  bool pw = true;
  #pragma unroll
  for (int i=1;i<16;i++) pw = pw && (fabsf(A[i] - (float)(i+1)*A[0]) <= 1e-3f*fabsf(A[i]));
  float Dd = Dp[d];
  size_t o = (size_t)(c*BATCH + b)*512 + d;
  const unsigned short* Hp = Hbuf + o*16;
  u16x8 h0 = *(const u16x8*)(Hp+0);
  u16x8 h1 = *(const u16x8*)(Hp+8);
  float h[16];
  #pragma unroll
  for (int i=0;i<8;i++){ h[i] = bf2f(h0[i]); h[8+i] = bf2f(h1[i]); }
  size_t rowbase = (size_t)b*SEQ + (size_t)c*CL;
  const unsigned short* dptr = dlt + rowbase*512 + d;
  unsigned short*       uptr = u   + rowbase*512 + d;
  const unsigned short* zptr = xz  + rowbase*1024 + 512 + d;
  const float*          bptr = xdb + rowbase*32;
  if (pw) pass3_body<true >(dptr, uptr, zptr, bptr, A, h, Dd);
  else    pass3_body<false>(dptr, uptr, zptr, bptr, A, h, Dd);
}

extern "C" void kernel_launch(void* const* d_in, const int* in_sizes, int n_in,
                              void* d_out, int out_size, void* d_ws, size_t ws_size,
                              hipStream_t stream){
  (void)in_sizes; (void)n_in; (void)out_size; (void)ws_size;
  const float* x      = (const float*)d_in[0];
  const float* W_in   = (const float*)d_in[1];
  const float* conv_w = (const float*)d_in[2];
  const float* conv_b = (const float*)d_in[3];
  const float* W_x    = (const float*)d_in[4];
  const float* W_dt   = (const float*)d_in[5];
  const float* b_dt   = (const float*)d_in[6];
  const float* A_log  = (const float*)d_in[7];
  const float* Dp     = (const float*)d_in[8];
  const float* W_out  = (const float*)d_in[9];
  const float* ln_g   = (const float*)d_in[10];
  const float* ln_b   = (const float*)d_in[11];
  float* out = (float*)d_out;

  // workspace carve-up (~198 MB)
  char* p = (char*)d_ws;
  auto alloc = [&](size_t bytes)->char*{
    char* r = p; p += (bytes + 255) & ~(size_t)255; return r;
  };
  float*          hbuf   = (float*)alloc((size_t)MROWS*DM*4);           // 33.5 MB residual f32
  unsigned short* xzb    = (unsigned short*)alloc((size_t)MROWS*1024*2);// 67 MB
  unsigned short* ubuf   = (unsigned short*)alloc((size_t)MROWS*DI*2);  // 33.5 MB (u, then gated g)
  unsigned short* lnb    = (unsigned short*)alloc((size_t)MROWS*DI*2);  // 33.5 MB shared: lnb / delta
  unsigned short* dlt    = lnb;                                         // alias (disjoint live ranges)
  float*          xdbc   = (float*)alloc((size_t)MROWS*32*4);           // 4.2 MB (B,C)
  unsigned short* WinB   = (unsigned short*)alloc((size_t)NL*1024*DM*2);// 3.1 MB
  unsigned short* WxB    = (unsigned short*)alloc((size_t)NL*48*DI*2);  // 0.3 MB
  unsigned short* WoutB  = (unsigned short*)alloc((size_t)NL*DM*DI*2);  // 1.6 MB
  unsigned short* WeffB  = (unsigned short*)alloc((size_t)NL*DI*DI*2);  // 3.1 MB
  float*          sumdvB = (float*)alloc((size_t)CCH*BATCH*DI*4);       // 2.1 MB
  unsigned short* Hbuf   = (unsigned short*)alloc((size_t)CCH*SC*2);    // 16.8 MB bf16

  // weight conversion + W_eff precompute
  {
    int n1 = NL*1024*DM;  cvt_bf16<<<(n1+255)/256, 256, 0, stream>>>(W_in,  WinB,  n1);
    int n2 = NL*48*DI;    cvt_bf16<<<(n2+255)/256, 256, 0, stream>>>(W_x,   WxB,   n2);
    int n3 = NL*DM*DI;    cvt_bf16<<<(n3+255)/256, 256, 0, stream>>>(W_out, WoutB, n3);
    weff_kernel<<<NL*DI*DI/256, 256, 0, stream>>>(W_dt, W_x, WeffB);
  }

  transpose_in<<<dim3(SEQ/32, DM/32, BATCH), dim3(32,8), 0, stream>>>(x, hbuf);

  for (int i=0; i<NL; i++){
    const unsigned short* Wi = WinB  + (size_t)i*1024*DM;
    const unsigned short* Wx = WxB   + (size_t)i*48*DI + 16*DI;  // B,C rows only
    const unsigned short* Wo = WoutB + (size_t)i*DM*DI;
    const unsigned short* We = WeffB + (size_t)i*DI*DI;
    const float* Al = A_log + (size_t)i*DI*DS;

    ln_kernel<<<MROWS/4, 256, 0, stream>>>(hbuf, ln_g + i*DM, ln_b + i*DM, lnb);

    // xz = ln @ W_in^T  [M,1024] bf16
    gemm_lds<1><<<dim3(1024/128, MROWS/128), 256, 0, stream>>>(lnb, Wi, xzb, nullptr, 1024, DM);

    conv_kernel<<<MROWS*64/256, 256, 0, stream>>>(xzb, conv_w + (size_t)i*DI*4,
                                                  conv_b + i*DI, ubuf);

    // xdbc = u @ Wx[16:48]^T  [M,32] f32 (B,C)
    gemm_lds<0><<<dim3(1, MROWS/128), 256, 0, stream>>>(ubuf, Wx, xdbc, nullptr, 32, DI);

    // delta = softplus(u @ W_eff^T + b_dt)  [M,512] bf16
    gemm_lds<3><<<dim3(DI/128, MROWS/128), 256, 0, stream>>>(ubuf, We, dlt, b_dt + i*DI, DI, DI);

    scan_pass1<<<BATCH*CCH*2, 256, 0, stream>>>(dlt, ubuf, xdbc, Al, sumdvB, Hbuf);
    scan_pass2<<<SC/256, 256, 0, stream>>>(sumdvB, Al, Hbuf);
    scan_pass3<<<BATCH*CCH*2, 256, 0, stream>>>(dlt, ubuf, xzb, xdbc, Al, Dp + i*DI, Hbuf);

    // h += g @ W_out^T  [M,256] f32 accumulate
    gemm_lds<2><<<dim3(DM/128, MROWS/128), 256, 0, stream>>>(ubuf, Wo, hbuf, nullptr, DM, DI);
  }

  transpose_out<<<dim3(SEQ/32, DM/32, BATCH), dim3(32,8), 0, stream>>>(hbuf, out);
}